// Round 10
// baseline (1810.110 us; speedup 1.0000x reference)
//
#include <hip/hip_runtime.h>
#include <hip/hip_bf16.h>

// GRU encoder: B=64, T=100, E=512, U=512.
// d_out = FLOAT32: output [B,T,U] then states [2,B,U].
// Scan: packed-u32 (hi|lo) LLC exchange, direct-to-register A-fragments.
// FIX vs round 9: sched_barrier(0) after vmcnt drain in load_frags — hipcc
// hoists register-only consumers (unpack/MFMA) past inline-asm s_waitcnt
// (pitfall m214 r263/r282); the barrier pins them after the drain.

#define TT 100

using f32x4 = __attribute__((ext_vector_type(4))) float;
using s16x8 = __attribute__((ext_vector_type(8))) short;
using u32x4 = __attribute__((ext_vector_type(4))) unsigned;

__device__ __forceinline__ unsigned short f2bfu(float x) {
  __hip_bfloat16 b = __float2bfloat16(x);
  unsigned short u;
  __builtin_memcpy(&u, &b, sizeof(u));
  return u;
}
__device__ __forceinline__ float bfu2f(unsigned short u) {
  __hip_bfloat16 b;
  __builtin_memcpy(&b, &u, sizeof(b));
  return __bfloat162float(b);
}
__device__ __forceinline__ float sigm(float x) {
  x = fminf(fmaxf(x, -30.f), 30.f);
  return 1.f / (1.f + __expf(-x));
}
__device__ __forceinline__ float tanh_fast(float x) {
  x = fminf(fmaxf(x, -15.f), 15.f);
  float e = __expf(-2.f * x);
  return (1.f - e) / (1.f + e);
}
__device__ __forceinline__ void vm_drain() {
  asm volatile("s_waitcnt vmcnt(0)" ::: "memory");
}

// ------------------------------------------------- pack weights (full K)
// Fragment layout [nt 0..95][kt 0..ktTot-1][lane 0..63][elem 0..7], hi/lo.
__global__ __launch_bounds__(256) void pack_w_kernel(const float* __restrict__ Wg,
                                                     const float* __restrict__ Wc,
                                                     int ldg, int ldc, int ktTot,
                                                     unsigned short* __restrict__ hi,
                                                     unsigned short* __restrict__ lo) {
  const int gg = blockIdx.x * 256 + threadIdx.x;
  if (gg >= 96 * ktTot * 64) return;
  const int lane = gg & 63;
  const int pair = gg >> 6;
  const int kt = pair % ktTot;
  const int nt = pair / ktTot;
  const int kg = lane >> 4;
  const int nl = lane & 15;
  const size_t off = (size_t)gg * 8;
  for (int i = 0; i < 8; ++i) {
    const int k = kt * 32 + kg * 8 + i;
    float v = (nt < 64) ? Wg[(size_t)k * ldg + nt * 16 + nl]
                        : Wc[(size_t)k * ldc + (nt - 64) * 16 + nl];
    unsigned short h = f2bfu(v);
    hi[off + i] = h;
    lo[off + i] = f2bfu(v - bfu2f(h));
  }
}

// --------------------------------------------- split-bf16 MFMA input GEMM
template <int ASRC>
__global__ __launch_bounds__(256) void gemm_mfma(
    const int* __restrict__ xtok, const float* __restrict__ emb,
    const unsigned short* __restrict__ aHi, const unsigned short* __restrict__ aLo, int lda,
    const unsigned short* __restrict__ bHi, const unsigned short* __restrict__ bLo,
    int ktTot, int ktX,
    const float* __restrict__ bg, const float* __restrict__ bc,
    float* __restrict__ C) {
  __shared__ unsigned short Ah[128 * 40];
  __shared__ unsigned short Al[128 * 40];

  const int tid = threadIdx.x;
  const int lane = tid & 63;
  const int w = tid >> 6;
  const int bm = blockIdx.x, bn = blockIdx.y;
  const int fm = lane & 15, fkg = lane >> 4;

  const int arow = tid >> 1;
  const int koff = (tid & 1) * 16;
  const int rowg = bm * 128 + arow;
  int embIdx = 0;
  if (ASRC == 0) {
    const int t_ = rowg >> 6, b_ = rowg & 63;
    embIdx = xtok[b_ * TT + t_];
  }

  f32x4 acc[2][8];
#pragma unroll
  for (int rt = 0; rt < 2; ++rt)
#pragma unroll
    for (int ni = 0; ni < 8; ++ni) acc[rt][ni] = (f32x4){0.f, 0.f, 0.f, 0.f};

  for (int kt = 0; kt < ktX; ++kt) {
    __syncthreads();
    if (ASRC == 0) {
      const float* src = emb + (size_t)embIdx * 512 + kt * 32 + koff;
      s16x8 h0, h1, l0, l1;
#pragma unroll
      for (int c = 0; c < 2; ++c) {
        f32x4 va = *(const f32x4*)(src + c * 8);
        f32x4 vb = *(const f32x4*)(src + c * 8 + 4);
        s16x8 hh, ll;
#pragma unroll
        for (int j = 0; j < 4; ++j) {
          unsigned short h = f2bfu(va[j]);
          hh[j] = (short)h; ll[j] = (short)f2bfu(va[j] - bfu2f(h));
          unsigned short h2 = f2bfu(vb[j]);
          hh[j + 4] = (short)h2; ll[j + 4] = (short)f2bfu(vb[j] - bfu2f(h2));
        }
        if (c == 0) { h0 = hh; l0 = ll; } else { h1 = hh; l1 = ll; }
      }
      *(s16x8*)(Ah + arow * 40 + koff) = h0;
      *(s16x8*)(Ah + arow * 40 + koff + 8) = h1;
      *(s16x8*)(Al + arow * 40 + koff) = l0;
      *(s16x8*)(Al + arow * 40 + koff + 8) = l1;
    } else {
      const size_t so = (size_t)rowg * lda + kt * 32 + koff;
      s16x8 h0 = *(const s16x8*)(aHi + so);
      s16x8 h1 = *(const s16x8*)(aHi + so + 8);
      s16x8 l0 = *(const s16x8*)(aLo + so);
      s16x8 l1 = *(const s16x8*)(aLo + so + 8);
      *(s16x8*)(Ah + arow * 40 + koff) = h0;
      *(s16x8*)(Ah + arow * 40 + koff + 8) = h1;
      *(s16x8*)(Al + arow * 40 + koff) = l0;
      *(s16x8*)(Al + arow * 40 + koff + 8) = l1;
    }
    __syncthreads();

    s16x8 ah[2], al[2];
#pragma unroll
    for (int rt = 0; rt < 2; ++rt) {
      const int m = w * 32 + rt * 16 + fm;
      ah[rt] = *(const s16x8*)(Ah + m * 40 + fkg * 8);
      al[rt] = *(const s16x8*)(Al + m * 40 + fkg * 8);
    }
#pragma unroll
    for (int ni = 0; ni < 8; ++ni) {
      const int nt = bn * 8 + ni;
      const size_t bo = ((size_t)nt * ktTot + kt) * 512 + lane * 8;
      s16x8 bh = *(const s16x8*)(bHi + bo);
      s16x8 bl = *(const s16x8*)(bLo + bo);
#pragma unroll
      for (int rt = 0; rt < 2; ++rt) {
        acc[rt][ni] = __builtin_amdgcn_mfma_f32_16x16x32_bf16(ah[rt], bh, acc[rt][ni], 0, 0, 0);
        acc[rt][ni] = __builtin_amdgcn_mfma_f32_16x16x32_bf16(ah[rt], bl, acc[rt][ni], 0, 0, 0);
        acc[rt][ni] = __builtin_amdgcn_mfma_f32_16x16x32_bf16(al[rt], bh, acc[rt][ni], 0, 0, 0);
      }
    }
  }

#pragma unroll
  for (int ni = 0; ni < 8; ++ni) {
    const int nt = bn * 8 + ni;
    int dcol; float bias;
    if (nt < 64) { dcol = nt * 16 + fm; bias = bg[dcol]; }
    else { dcol = 1024 + (nt - 64) * 16 + fm; bias = bc[(nt - 64) * 16 + fm]; }
#pragma unroll
    for (int rt = 0; rt < 2; ++rt)
#pragma unroll
      for (int j = 0; j < 4; ++j) {
        const int row = bm * 128 + w * 32 + rt * 16 + fkg * 4 + j;
        C[(size_t)row * 1536 + dcol] = acc[rt][ni][j] + bias;
      }
  }
}

// ------------------------------------------------------------- GRU scan
// 8 groups x 32 WGs; WG owns hidden cols [wg*16, wg*16+16). Exchange tiles:
// one u32 per (batch,col) = bf16hi | bf16lo<<16, swizzled col index, in LLC.
template <int NB>
__global__ __launch_bounds__(256, 1) void gru_scan_kernel(
    const float* __restrict__ gxF, const float* __restrict__ gxB,
    const unsigned short* __restrict__ wHiF, const unsigned short* __restrict__ wLoF,
    const unsigned short* __restrict__ wHiB, const unsigned short* __restrict__ wLoB,
    int ktTot, int ktH0,
    unsigned* __restrict__ hPkG, unsigned* __restrict__ rPkG,
    unsigned* __restrict__ slots,
    unsigned short* __restrict__ yHi, unsigned short* __restrict__ yLo, int yld,
    float* __restrict__ outb,
    float* __restrict__ stout) {
  __shared__ unsigned short wHi_s[3 * 8192];   // 48KB: [r|u|c] h-part tiles
  __shared__ unsigned short wLo_s[3 * 8192];   // 48KB
  __shared__ float scr[4][16][17];             // r / cand partials
  __shared__ float scr2[4][16][17];            // u partials

  const int tid = threadIdx.x;
  const int lane = tid & 63;
  const int wv = tid >> 6;
  const int bid = blockIdx.x;
  const int g = bid & 7;
  const int wg = bid >> 3;
  const int hs = wg << 4;

  int dir = 0, b0;
  const float* gx;
  const unsigned short *wph, *wpl;
  if (NB == 16) {
    dir = g & 1;
    b0 = (g >> 1) << 4;
    gx = dir ? gxB : gxF;
    wph = dir ? wHiB : wHiF;
    wpl = dir ? wLoB : wLoF;
  } else {
    b0 = g * NB;
    gx = gxF;
    wph = wHiF;
    wpl = wLoF;
  }

  // stationary weight fragments (h-part) -> LDS
  {
    const int nt0[3] = {wg, 32 + wg, 64 + wg};
    for (int c = 0; c < 3; ++c) {
      const unsigned short* sH = wph + ((size_t)nt0[c] * ktTot + ktH0) * 512;
      const unsigned short* sL = wpl + ((size_t)nt0[c] * ktTot + ktH0) * 512;
      unsigned short* dH = wHi_s + c * 8192;
      unsigned short* dL = wLo_s + c * 8192;
#pragma unroll
      for (int it = 0; it < 4; ++it) {
        const int o = (it * 256 + tid) * 8;
        *(s16x8*)(dH + o) = *(const s16x8*)(sH + o);
        *(s16x8*)(dL + o) = *(const s16x8*)(sL + o);
      }
    }
  }
  __syncthreads();

  unsigned* gslots = slots + g * 32;

  // MFMA lane constants (A: row=batch=fm, k-group=fkg)
  const int fm = lane & 15;
  const int fkg = lane >> 4;
  const int afe = fm * 512;           // tile entry base for this lane's batch row
  const int asw = (fm & 7) << 3;      // col-index XOR swizzle (entry units)

  // owner mapping: batch = tid>>4, col = tid&15
  const int ob = tid >> 4, oj = tid & 15;
  const bool own = (ob < NB);
  const int ui = ob * 512 + ((hs + oj) ^ ((ob & 7) << 3));

  const size_t tileo = (size_t)g * 8192;   // u32 entries per group tile

  auto mfma_regs = [&](int cidx, const s16x8* ah, const s16x8* al,
                       float (*dst)[16][17]) {
    f32x4 acc0 = {0.f, 0.f, 0.f, 0.f}, acc1 = {0.f, 0.f, 0.f, 0.f};
#pragma unroll
    for (int q = 0; q < 4; ++q) {
      const int kt = wv * 4 + q;
      const int wo = ((cidx * 16 + kt) * 64 + lane) * 8;
      s16x8 bh = *(const s16x8*)(wHi_s + wo);
      s16x8 bl = *(const s16x8*)(wLo_s + wo);
      if (q & 1) {
        acc1 = __builtin_amdgcn_mfma_f32_16x16x32_bf16(ah[q], bh, acc1, 0, 0, 0);
        acc1 = __builtin_amdgcn_mfma_f32_16x16x32_bf16(ah[q], bl, acc1, 0, 0, 0);
        acc1 = __builtin_amdgcn_mfma_f32_16x16x32_bf16(al[q], bh, acc1, 0, 0, 0);
      } else {
        acc0 = __builtin_amdgcn_mfma_f32_16x16x32_bf16(ah[q], bh, acc0, 0, 0, 0);
        acc0 = __builtin_amdgcn_mfma_f32_16x16x32_bf16(ah[q], bl, acc0, 0, 0, 0);
        acc0 = __builtin_amdgcn_mfma_f32_16x16x32_bf16(al[q], bh, acc0, 0, 0, 0);
      }
    }
#pragma unroll
    for (int j = 0; j < 4; ++j) dst[wv][fkg * 4 + j][fm] = acc0[j] + acc1[j];
  };

  // load this wave's A-fragments directly from an LLC tile; unpack hi/lo.
  auto load_frags = [&](const unsigned* pk, s16x8* ah, s16x8* al,
                        bool withHv, unsigned* hvOut) {
    u32x4 d[4][2];
#pragma unroll
    for (int q = 0; q < 4; ++q) {
      const int kt = wv * 4 + q;
      const unsigned* p = pk + tileo + afe + ((kt * 32 + fkg * 8) ^ asw);
      asm volatile("global_load_dwordx4 %0, %1, off sc0 sc1"
                   : "=v"(d[q][0]) : "v"(p) : "memory");
      asm volatile("global_load_dwordx4 %0, %1, off sc0 sc1"
                   : "=v"(d[q][1]) : "v"(p + 4) : "memory");
    }
    if (withHv && own)
      asm volatile("global_load_dword %0, %1, off sc0 sc1"
                   : "=v"(*hvOut) : "v"(pk + tileo + ui) : "memory");
    vm_drain();
    // PIN register-only consumers after the drain (pitfall m214 r263/r282):
    __builtin_amdgcn_sched_barrier(0);
#pragma unroll
    for (int q = 0; q < 4; ++q) {
      u32x4 hh, ll;
#pragma unroll
      for (int i = 0; i < 2; ++i) {
        const u32x4 dd = d[q][i];
        hh[2 * i] = (dd[0] & 0xffffu) | (dd[1] << 16);
        hh[2 * i + 1] = (dd[2] & 0xffffu) | (dd[3] << 16);
        ll[2 * i] = (dd[0] >> 16) | (dd[1] & 0xffff0000u);
        ll[2 * i + 1] = (dd[2] >> 16) | (dd[3] & 0xffff0000u);
      }
      __builtin_memcpy(&ah[q], &hh, 16);
      __builtin_memcpy(&al[q], &ll, 16);
    }
  };

  auto poll = [&](unsigned target) {
    if (tid < 32) {
      const unsigned* p = gslots + tid;
      unsigned v;
      do {
        asm volatile("global_load_dword %0, %1, off sc0 sc1\n\ts_waitcnt vmcnt(0)"
                     : "=v"(v) : "v"(p) : "memory");
      } while (!__all(v >= target));
    }
    __syncthreads();
  };

  // gx prefetch for step 0
  float gxr = 0.f, gxu = 0.f, gxc = 0.f;
  if (own) {
    const float* row = gx + ((size_t)(dir ? TT - 1 : 0) * 64 + b0 + ob) * 1536 + hs + oj;
    gxr = row[0]; gxu = row[512]; gxc = row[1024];
  }

  for (int t = 0; t < TT; ++t) {
    const int tg = dir ? (TT - 1 - t) : t;

    // ---- G1r: h fragments from LLC (t=0: zeroed tile) + r MFMAs ----
    s16x8 ah[4], al[4];
    unsigned hvu = 0;
    load_frags(hPkG, ah, al, true, &hvu);
    mfma_regs(0, ah, al, scr);
    __syncthreads();

    // ---- S1: sigmoid(r), store r*h packed u32 ----
    float hv = 0.f;
    if (own) {
      float rpre = scr[0][ob][oj] + scr[1][ob][oj] + scr[2][ob][oj] + scr[3][ob][oj] + gxr;
      float sg = sigm(rpre);
      hv = bfu2f((unsigned short)(hvu & 0xffffu)) + bfu2f((unsigned short)(hvu >> 16));
      float rh = sg * hv;
      unsigned short hh_ = f2bfu(rh);
      unsigned short ll_ = f2bfu(rh - bfu2f(hh_));
      unsigned e = (unsigned)hh_ | ((unsigned)ll_ << 16);
      asm volatile("global_store_dword %0, %1, off sc0 sc1"
                   :: "v"(rPkG + tileo + ui), "v"(e) : "memory");
    }
    vm_drain();
    __syncthreads();
    if (tid == 0) {
      unsigned tv = 2 * t + 1;
      asm volatile("global_store_dword %0, %1, off sc0 sc1"
                   :: "v"(gslots + wg), "v"(tv) : "memory");
    }

    // ---- G1u: u-gate MFMAs on retained A regs (covers flag latency) ----
    mfma_regs(1, ah, al, scr2);

    // ---- prefetch next step's gx ----
    float ngxr = 0.f, ngxu = 0.f, ngxc = 0.f;
    if (own && t + 1 < TT) {
      const int tgn = dir ? (TT - 2 - t) : (t + 1);
      const float* row = gx + ((size_t)tgn * 64 + b0 + ob) * 1536 + hs + oj;
      ngxr = row[0]; ngxu = row[512]; ngxc = row[1024];
    }

    poll(2 * t + 1);

    // ---- G2: r*h fragments from LLC + candidate MFMAs ----
    load_frags(rPkG, ah, al, false, nullptr);
    mfma_regs(2, ah, al, scr);
    __syncthreads();

    // ---- S2: u from scr2, tanh, h update ----
    float hn = 0.f;
    unsigned short hh_ = 0, ll_ = 0;
    if (own) {
      float upre = scr2[0][ob][oj] + scr2[1][ob][oj] + scr2[2][ob][oj] + scr2[3][ob][oj] + gxu;
      float uv = sigm(upre);
      float cpre = scr[0][ob][oj] + scr[1][ob][oj] + scr[2][ob][oj] + scr[3][ob][oj] + gxc;
      float cv = tanh_fast(cpre);
      hn = uv * hv + (1.f - uv) * cv;
      hh_ = f2bfu(hn);
      ll_ = f2bfu(hn - bfu2f(hh_));
    }

    if (t == TT - 1) {
      if (own) {
        if (yHi) {
          const int ycol = (NB == 16) ? (dir * 512 + hs + oj) : (hs + oj);
          const size_t yi = ((size_t)tg * 64 + (b0 + ob)) * yld + ycol;
          yHi[yi] = hh_; yLo[yi] = ll_;
        }
        if (outb) outb[((size_t)(b0 + ob) * TT + t) * 512 + hs + oj] = hn;
        if (stout) stout[(size_t)(b0 + ob) * 512 + hs + oj] = hn;
      }
      break;
    }

    if (own) {
      unsigned e = (unsigned)hh_ | ((unsigned)ll_ << 16);
      asm volatile("global_store_dword %0, %1, off sc0 sc1"
                   :: "v"(hPkG + tileo + ui), "v"(e) : "memory");
    }
    vm_drain();
    __syncthreads();
    if (tid == 0) {
      unsigned tv = 2 * t + 2;
      asm volatile("global_store_dword %0, %1, off sc0 sc1"
                   :: "v"(gslots + wg), "v"(tv) : "memory");
    }

    // ---- y-writes overlap the poll ----
    if (own) {
      if (yHi) {
        const int ycol = (NB == 16) ? (dir * 512 + hs + oj) : (hs + oj);
        const size_t yi = ((size_t)tg * 64 + (b0 + ob)) * yld + ycol;
        yHi[yi] = hh_; yLo[yi] = ll_;
      }
      if (outb) outb[((size_t)(b0 + ob) * TT + t) * 512 + hs + oj] = hn;
    }
    gxr = ngxr; gxu = ngxu; gxc = ngxc;

    poll(2 * t + 2);
  }
}

// ---------------------------------------------------------------- launcher
extern "C" void kernel_launch(void* const* d_in, const int* in_sizes, int n_in,
                              void* d_out, int out_size, void* d_ws, size_t ws_size,
                              hipStream_t stream) {
  (void)in_sizes; (void)n_in; (void)out_size; (void)ws_size;
  const int* x = (const int*)d_in[0];
  const float* emb = (const float*)d_in[1];
  const float* WgFw = (const float*)d_in[2];
  const float* bgFw = (const float*)d_in[3];
  const float* WcFw = (const float*)d_in[4];
  const float* bcFw = (const float*)d_in[5];
  const float* WgBw = (const float*)d_in[6];
  const float* bgBw = (const float*)d_in[7];
  const float* WcBw = (const float*)d_in[8];
  const float* bcBw = (const float*)d_in[9];
  const float* WgU1 = (const float*)d_in[10];
  const float* bgU1 = (const float*)d_in[11];
  const float* WcU1 = (const float*)d_in[12];
  const float* bcU1 = (const float*)d_in[13];
  const float* WgU2 = (const float*)d_in[14];
  const float* bgU2 = (const float*)d_in[15];
  const float* WcU2 = (const float*)d_in[16];
  const float* bcU2 = (const float*)d_in[17];

  char* ws = (char*)d_ws;
  float* bufA = (float*)(ws + 0);                    // 39,321,600
  float* bufB = (float*)(ws + 39321600);             // 39,321,600
  unsigned short* ycatHi = (unsigned short*)(ws + 78643200);   // 13,107,200
  unsigned short* ycatLo = (unsigned short*)(ws + 91750400);   // 13,107,200
  unsigned short* y1Hi = (unsigned short*)(ws + 78643200);     // overlay
  unsigned short* y1Lo = (unsigned short*)(ws + 85196800);
  unsigned short* wpFwHi = (unsigned short*)(ws + 104857600);
  unsigned short* wpFwLo = (unsigned short*)(ws + 108003328);
  unsigned short* wpBwHi = (unsigned short*)(ws + 111149056);
  unsigned short* wpBwLo = (unsigned short*)(ws + 114294784);
  unsigned short* wpU1Hi = (unsigned short*)(ws + 117440512);
  unsigned short* wpU1Lo = (unsigned short*)(ws + 122159104);
  unsigned short* wpU2Hi = (unsigned short*)(ws + 117440512);  // overlay after u1
  unsigned short* wpU2Lo = (unsigned short*)(ws + 120586240);
  unsigned* hPkG = (unsigned*)(ws + 126877696);      // 262,144 B packed h tile
  unsigned* rPkG = (unsigned*)(ws + 127139840);      // 262,144 B packed rh tile
  unsigned* bars = (unsigned*)(ws + 127401984);      // 4,096 B slot arrays

  float* out = (float*)d_out;
  float* st1 = out + (size_t)64 * TT * 512;
  float* st2 = st1 + 64 * 512;

  hipMemsetAsync(bars, 0, 4096, stream);

  pack_w_kernel<<<768, 256, 0, stream>>>(WgFw, WcFw, 1024, 512, 32, wpFwHi, wpFwLo);
  pack_w_kernel<<<768, 256, 0, stream>>>(WgBw, WcBw, 1024, 512, 32, wpBwHi, wpBwLo);
  pack_w_kernel<<<1152, 256, 0, stream>>>(WgU1, WcU1, 1024, 512, 48, wpU1Hi, wpU1Lo);

  gemm_mfma<0><<<dim3(50, 12), 256, 0, stream>>>(
      x, emb, nullptr, nullptr, 0, wpFwHi, wpFwLo, 32, 16, bgFw, bcFw, bufA);
  gemm_mfma<0><<<dim3(50, 12), 256, 0, stream>>>(
      x, emb, nullptr, nullptr, 0, wpBwHi, wpBwLo, 32, 16, bgBw, bcBw, bufB);

  hipMemsetAsync(hPkG, 0, 524288, stream);   // zero h + rh tiles (h(0)=0)
  {  // bidirectional scan -> ycat planes
    const float *a0 = bufA, *a1 = bufB;
    const unsigned short *w0 = wpFwHi, *w1 = wpFwLo, *w2 = wpBwHi, *w3 = wpBwLo;
    int ktT = 32, ktH = 16;
    unsigned *h0 = hPkG, *r0 = rPkG;
    unsigned* bp = bars;
    unsigned short *yh = ycatHi, *yl = ycatLo; int yld = 1024;
    float *on = nullptr, *sn = nullptr;
    void* args[] = {&a0, &a1, &w0, &w1, &w2, &w3, &ktT, &ktH, &h0, &r0,
                    &bp, &yh, &yl, &yld, &on, &sn};
    hipLaunchCooperativeKernel((const void*)gru_scan_kernel<16>, dim3(256), dim3(256),
                               args, 0, stream);
  }

  gemm_mfma<1><<<dim3(50, 12), 256, 0, stream>>>(
      nullptr, nullptr, ycatHi, ycatLo, 1024, wpU1Hi, wpU1Lo, 48, 32, bgU1, bcU1, bufA);

  hipMemsetAsync(hPkG, 0, 524288, stream);
  {  // u1 scan -> y1 planes + st1
    const float *a0 = bufA, *a1 = nullptr;
    const unsigned short *w0 = wpU1Hi, *w1 = wpU1Lo, *w2 = nullptr, *w3 = nullptr;
    int ktT = 48, ktH = 32;
    unsigned *h0 = hPkG, *r0 = rPkG;
    unsigned* bp = bars + 256;
    unsigned short *yh = y1Hi, *yl = y1Lo; int yld = 512;
    float *on = nullptr, *sn = st1;
    void* args[] = {&a0, &a1, &w0, &w1, &w2, &w3, &ktT, &ktH, &h0, &r0,
                    &bp, &yh, &yl, &yld, &on, &sn};
    hipLaunchCooperativeKernel((const void*)gru_scan_kernel<8>, dim3(256), dim3(256),
                               args, 0, stream);
  }

  pack_w_kernel<<<768, 256, 0, stream>>>(WgU2, WcU2, 1024, 512, 32, wpU2Hi, wpU2Lo);

  gemm_mfma<1><<<dim3(50, 12), 256, 0, stream>>>(
      nullptr, nullptr, y1Hi, y1Lo, 512, wpU2Hi, wpU2Lo, 32, 16, bgU2, bcU2, bufB);

  hipMemsetAsync(hPkG, 0, 524288, stream);
  {  // u2 scan -> d_out (f32) + st2
    const float *a0 = bufB, *a1 = nullptr;
    const unsigned short *w0 = wpU2Hi, *w1 = wpU2Lo, *w2 = nullptr, *w3 = nullptr;
    int ktT = 32, ktH = 16;
    unsigned *h0 = hPkG, *r0 = rPkG;
    unsigned* bp = bars + 512;
    unsigned short *yh = nullptr, *yl = nullptr; int yld = 0;
    float *on = out, *sn = st2;
    void* args[] = {&a0, &a1, &w0, &w1, &w2, &w3, &ktT, &ktH, &h0, &r0,
                    &bp, &yh, &yl, &yld, &on, &sn};
    hipLaunchCooperativeKernel((const void*)gru_scan_kernel<8>, dim3(256), dim3(256),
                               args, 0, stream);
  }
}

// Round 12
// 1590.897 us; speedup vs baseline: 1.1378x; 1.1378x over previous
//
#include <hip/hip_runtime.h>
#include <hip/hip_bf16.h>

// GRU encoder: B=64, T=100, E=512, U=512.
// d_out = FLOAT32: output [B,T,U] then states [2,B,U].
// Bidir scan = round-10 proven kernel (sc1 exchange + monotonic flags).
// u1+u2 fused: u1 (128 WGs) and u2 (128 WGs) run concurrently; u2 lags one
// step, consumes y1 via sc1+flags, computes its x-projection on the fly.

#define TT 100

using f32x4 = __attribute__((ext_vector_type(4))) float;
using s16x8 = __attribute__((ext_vector_type(8))) short;
using u32x4 = __attribute__((ext_vector_type(4))) unsigned;

__device__ __forceinline__ unsigned short f2bfu(float x) {
  __hip_bfloat16 b = __float2bfloat16(x);
  unsigned short u;
  __builtin_memcpy(&u, &b, sizeof(u));
  return u;
}
__device__ __forceinline__ float bfu2f(unsigned short u) {
  __hip_bfloat16 b;
  __builtin_memcpy(&b, &u, sizeof(b));
  return __bfloat162float(b);
}
__device__ __forceinline__ float sigm(float x) {
  x = fminf(fmaxf(x, -30.f), 30.f);
  return 1.f / (1.f + __expf(-x));
}
__device__ __forceinline__ float tanh_fast(float x) {
  x = fminf(fmaxf(x, -15.f), 15.f);
  float e = __expf(-2.f * x);
  return (1.f - e) / (1.f + e);
}
__device__ __forceinline__ void vm_drain() {
  asm volatile("s_waitcnt vmcnt(0)" ::: "memory");
}
__device__ __forceinline__ void sc1_store_b16(void* p, unsigned v) {
  asm volatile("global_store_short %0, %1, off sc0 sc1" :: "v"(p), "v"(v) : "memory");
}

// ------------------------------------------------- pack weights (full K)
// Fragment layout [nt 0..95][kt 0..ktTot-1][lane 0..63][elem 0..7], hi/lo.
__global__ __launch_bounds__(256) void pack_w_kernel(const float* __restrict__ Wg,
                                                     const float* __restrict__ Wc,
                                                     int ldg, int ldc, int ktTot,
                                                     unsigned short* __restrict__ hi,
                                                     unsigned short* __restrict__ lo) {
  const int gg = blockIdx.x * 256 + threadIdx.x;
  if (gg >= 96 * ktTot * 64) return;
  const int lane = gg & 63;
  const int pair = gg >> 6;
  const int kt = pair % ktTot;
  const int nt = pair / ktTot;
  const int kg = lane >> 4;
  const int nl = lane & 15;
  const size_t off = (size_t)gg * 8;
  for (int i = 0; i < 8; ++i) {
    const int k = kt * 32 + kg * 8 + i;
    float v = (nt < 64) ? Wg[(size_t)k * ldg + nt * 16 + nl]
                        : Wc[(size_t)k * ldc + (nt - 64) * 16 + nl];
    unsigned short h = f2bfu(v);
    hi[off + i] = h;
    lo[off + i] = f2bfu(v - bfu2f(h));
  }
}

// --------------------------------------------- split-bf16 MFMA input GEMM
template <int ASRC>
__global__ __launch_bounds__(256) void gemm_mfma(
    const int* __restrict__ xtok, const float* __restrict__ emb,
    const unsigned short* __restrict__ aHi, const unsigned short* __restrict__ aLo, int lda,
    const unsigned short* __restrict__ bHi, const unsigned short* __restrict__ bLo,
    int ktTot, int ktX,
    const float* __restrict__ bg, const float* __restrict__ bc,
    float* __restrict__ C) {
  __shared__ unsigned short Ah[128 * 40];
  __shared__ unsigned short Al[128 * 40];

  const int tid = threadIdx.x;
  const int lane = tid & 63;
  const int w = tid >> 6;
  const int bm = blockIdx.x, bn = blockIdx.y;
  const int fm = lane & 15, fkg = lane >> 4;

  const int arow = tid >> 1;
  const int koff = (tid & 1) * 16;
  const int rowg = bm * 128 + arow;
  int embIdx = 0;
  if (ASRC == 0) {
    const int t_ = rowg >> 6, b_ = rowg & 63;
    embIdx = xtok[b_ * TT + t_];
  }

  f32x4 acc[2][8];
#pragma unroll
  for (int rt = 0; rt < 2; ++rt)
#pragma unroll
    for (int ni = 0; ni < 8; ++ni) acc[rt][ni] = (f32x4){0.f, 0.f, 0.f, 0.f};

  for (int kt = 0; kt < ktX; ++kt) {
    __syncthreads();
    if (ASRC == 0) {
      const float* src = emb + (size_t)embIdx * 512 + kt * 32 + koff;
      s16x8 h0, h1, l0, l1;
#pragma unroll
      for (int c = 0; c < 2; ++c) {
        f32x4 va = *(const f32x4*)(src + c * 8);
        f32x4 vb = *(const f32x4*)(src + c * 8 + 4);
        s16x8 hh, ll;
#pragma unroll
        for (int j = 0; j < 4; ++j) {
          unsigned short h = f2bfu(va[j]);
          hh[j] = (short)h; ll[j] = (short)f2bfu(va[j] - bfu2f(h));
          unsigned short h2 = f2bfu(vb[j]);
          hh[j + 4] = (short)h2; ll[j + 4] = (short)f2bfu(vb[j] - bfu2f(h2));
        }
        if (c == 0) { h0 = hh; l0 = ll; } else { h1 = hh; l1 = ll; }
      }
      *(s16x8*)(Ah + arow * 40 + koff) = h0;
      *(s16x8*)(Ah + arow * 40 + koff + 8) = h1;
      *(s16x8*)(Al + arow * 40 + koff) = l0;
      *(s16x8*)(Al + arow * 40 + koff + 8) = l1;
    } else {
      const size_t so = (size_t)rowg * lda + kt * 32 + koff;
      s16x8 h0 = *(const s16x8*)(aHi + so);
      s16x8 h1 = *(const s16x8*)(aHi + so + 8);
      s16x8 l0 = *(const s16x8*)(aLo + so);
      s16x8 l1 = *(const s16x8*)(aLo + so + 8);
      *(s16x8*)(Ah + arow * 40 + koff) = h0;
      *(s16x8*)(Ah + arow * 40 + koff + 8) = h1;
      *(s16x8*)(Al + arow * 40 + koff) = l0;
      *(s16x8*)(Al + arow * 40 + koff + 8) = l1;
    }
    __syncthreads();

    s16x8 ah[2], al[2];
#pragma unroll
    for (int rt = 0; rt < 2; ++rt) {
      const int m = w * 32 + rt * 16 + fm;
      ah[rt] = *(const s16x8*)(Ah + m * 40 + fkg * 8);
      al[rt] = *(const s16x8*)(Al + m * 40 + fkg * 8);
    }
#pragma unroll
    for (int ni = 0; ni < 8; ++ni) {
      const int nt = bn * 8 + ni;
      const size_t bo = ((size_t)nt * ktTot + kt) * 512 + lane * 8;
      s16x8 bh = *(const s16x8*)(bHi + bo);
      s16x8 bl = *(const s16x8*)(bLo + bo);
#pragma unroll
      for (int rt = 0; rt < 2; ++rt) {
        acc[rt][ni] = __builtin_amdgcn_mfma_f32_16x16x32_bf16(ah[rt], bh, acc[rt][ni], 0, 0, 0);
        acc[rt][ni] = __builtin_amdgcn_mfma_f32_16x16x32_bf16(ah[rt], bl, acc[rt][ni], 0, 0, 0);
        acc[rt][ni] = __builtin_amdgcn_mfma_f32_16x16x32_bf16(al[rt], bh, acc[rt][ni], 0, 0, 0);
      }
    }
  }

#pragma unroll
  for (int ni = 0; ni < 8; ++ni) {
    const int nt = bn * 8 + ni;
    int dcol; float bias;
    if (nt < 64) { dcol = nt * 16 + fm; bias = bg[dcol]; }
    else { dcol = 1024 + (nt - 64) * 16 + fm; bias = bc[(nt - 64) * 16 + fm]; }
#pragma unroll
    for (int rt = 0; rt < 2; ++rt)
#pragma unroll
      for (int j = 0; j < 4; ++j) {
        const int row = bm * 128 + w * 32 + rt * 16 + fkg * 4 + j;
        C[(size_t)row * 1536 + dcol] = acc[rt][ni][j] + bias;
      }
  }
}

// ------------------------------------------------------------- bidir scan
// Round-10 proven kernel, unchanged.
template <int NB>
__global__ __launch_bounds__(256, 1) void gru_scan_kernel(
    const float* __restrict__ gxF, const float* __restrict__ gxB,
    const unsigned short* __restrict__ wHiF, const unsigned short* __restrict__ wLoF,
    const unsigned short* __restrict__ wHiB, const unsigned short* __restrict__ wLoB,
    int ktTot, int ktH0,
    unsigned* __restrict__ hPkG, unsigned* __restrict__ rPkG,
    unsigned* __restrict__ slots,
    unsigned short* __restrict__ yHi, unsigned short* __restrict__ yLo, int yld,
    float* __restrict__ outb,
    float* __restrict__ stout) {
  __shared__ unsigned short wHi_s[3 * 8192];
  __shared__ unsigned short wLo_s[3 * 8192];
  __shared__ float scr[4][16][17];
  __shared__ float scr2[4][16][17];

  const int tid = threadIdx.x;
  const int lane = tid & 63;
  const int wv = tid >> 6;
  const int bid = blockIdx.x;
  const int g = bid & 7;
  const int wg = bid >> 3;
  const int hs = wg << 4;

  int dir = 0, b0;
  const float* gx;
  const unsigned short *wph, *wpl;
  if (NB == 16) {
    dir = g & 1;
    b0 = (g >> 1) << 4;
    gx = dir ? gxB : gxF;
    wph = dir ? wHiB : wHiF;
    wpl = dir ? wLoB : wLoF;
  } else {
    b0 = g * NB;
    gx = gxF;
    wph = wHiF;
    wpl = wLoF;
  }

  {
    const int nt0[3] = {wg, 32 + wg, 64 + wg};
    for (int c = 0; c < 3; ++c) {
      const unsigned short* sH = wph + ((size_t)nt0[c] * ktTot + ktH0) * 512;
      const unsigned short* sL = wpl + ((size_t)nt0[c] * ktTot + ktH0) * 512;
      unsigned short* dH = wHi_s + c * 8192;
      unsigned short* dL = wLo_s + c * 8192;
#pragma unroll
      for (int it = 0; it < 4; ++it) {
        const int o = (it * 256 + tid) * 8;
        *(s16x8*)(dH + o) = *(const s16x8*)(sH + o);
        *(s16x8*)(dL + o) = *(const s16x8*)(sL + o);
      }
    }
  }
  __syncthreads();

  unsigned* gslots = slots + g * 32;

  const int fm = lane & 15;
  const int fkg = lane >> 4;
  const int afe = fm * 512;
  const int asw = (fm & 7) << 3;

  const int ob = tid >> 4, oj = tid & 15;
  const bool own = (ob < NB);
  const int ui = ob * 512 + ((hs + oj) ^ ((ob & 7) << 3));

  const size_t tileo = (size_t)g * 8192;

  auto mfma_regs = [&](int cidx, const s16x8* ah, const s16x8* al,
                       float (*dst)[16][17]) {
    f32x4 acc0 = {0.f, 0.f, 0.f, 0.f}, acc1 = {0.f, 0.f, 0.f, 0.f};
#pragma unroll
    for (int q = 0; q < 4; ++q) {
      const int kt = wv * 4 + q;
      const int wo = ((cidx * 16 + kt) * 64 + lane) * 8;
      s16x8 bh = *(const s16x8*)(wHi_s + wo);
      s16x8 bl = *(const s16x8*)(wLo_s + wo);
      if (q & 1) {
        acc1 = __builtin_amdgcn_mfma_f32_16x16x32_bf16(ah[q], bh, acc1, 0, 0, 0);
        acc1 = __builtin_amdgcn_mfma_f32_16x16x32_bf16(ah[q], bl, acc1, 0, 0, 0);
        acc1 = __builtin_amdgcn_mfma_f32_16x16x32_bf16(al[q], bh, acc1, 0, 0, 0);
      } else {
        acc0 = __builtin_amdgcn_mfma_f32_16x16x32_bf16(ah[q], bh, acc0, 0, 0, 0);
        acc0 = __builtin_amdgcn_mfma_f32_16x16x32_bf16(ah[q], bl, acc0, 0, 0, 0);
        acc0 = __builtin_amdgcn_mfma_f32_16x16x32_bf16(al[q], bh, acc0, 0, 0, 0);
      }
    }
#pragma unroll
    for (int j = 0; j < 4; ++j) dst[wv][fkg * 4 + j][fm] = acc0[j] + acc1[j];
  };

  auto load_frags = [&](const unsigned* pk, s16x8* ah, s16x8* al,
                        bool withHv, unsigned* hvOut) {
    u32x4 d[4][2];
#pragma unroll
    for (int q = 0; q < 4; ++q) {
      const int kt = wv * 4 + q;
      const unsigned* p = pk + tileo + afe + ((kt * 32 + fkg * 8) ^ asw);
      asm volatile("global_load_dwordx4 %0, %1, off sc0 sc1"
                   : "=v"(d[q][0]) : "v"(p) : "memory");
      asm volatile("global_load_dwordx4 %0, %1, off sc0 sc1"
                   : "=v"(d[q][1]) : "v"(p + 4) : "memory");
    }
    if (withHv && own)
      asm volatile("global_load_dword %0, %1, off sc0 sc1"
                   : "=v"(*hvOut) : "v"(pk + tileo + ui) : "memory");
    vm_drain();
    __builtin_amdgcn_sched_barrier(0);
#pragma unroll
    for (int q = 0; q < 4; ++q) {
      u32x4 hh, ll;
#pragma unroll
      for (int i = 0; i < 2; ++i) {
        const u32x4 dd = d[q][i];
        hh[2 * i] = (dd[0] & 0xffffu) | (dd[1] << 16);
        hh[2 * i + 1] = (dd[2] & 0xffffu) | (dd[3] << 16);
        ll[2 * i] = (dd[0] >> 16) | (dd[1] & 0xffff0000u);
        ll[2 * i + 1] = (dd[2] >> 16) | (dd[3] & 0xffff0000u);
      }
      __builtin_memcpy(&ah[q], &hh, 16);
      __builtin_memcpy(&al[q], &ll, 16);
    }
  };

  auto poll = [&](unsigned target) {
    if (tid < 32) {
      const unsigned* p = gslots + tid;
      unsigned v;
      do {
        asm volatile("global_load_dword %0, %1, off sc0 sc1\n\ts_waitcnt vmcnt(0)"
                     : "=v"(v) : "v"(p) : "memory");
      } while (!__all(v >= target));
    }
    __syncthreads();
  };

  float gxr = 0.f, gxu = 0.f, gxc = 0.f;
  if (own) {
    const float* row = gx + ((size_t)(dir ? TT - 1 : 0) * 64 + b0 + ob) * 1536 + hs + oj;
    gxr = row[0]; gxu = row[512]; gxc = row[1024];
  }

  for (int t = 0; t < TT; ++t) {
    const int tg = dir ? (TT - 1 - t) : t;

    s16x8 ah[4], al[4];
    unsigned hvu = 0;
    load_frags(hPkG, ah, al, true, &hvu);
    mfma_regs(0, ah, al, scr);
    __syncthreads();

    float hv = 0.f;
    if (own) {
      float rpre = scr[0][ob][oj] + scr[1][ob][oj] + scr[2][ob][oj] + scr[3][ob][oj] + gxr;
      float sg = sigm(rpre);
      hv = bfu2f((unsigned short)(hvu & 0xffffu)) + bfu2f((unsigned short)(hvu >> 16));
      float rh = sg * hv;
      unsigned short hh_ = f2bfu(rh);
      unsigned short ll_ = f2bfu(rh - bfu2f(hh_));
      unsigned e = (unsigned)hh_ | ((unsigned)ll_ << 16);
      asm volatile("global_store_dword %0, %1, off sc0 sc1"
                   :: "v"(rPkG + tileo + ui), "v"(e) : "memory");
    }
    vm_drain();
    __syncthreads();
    if (tid == 0) {
      unsigned tv = 2 * t + 1;
      asm volatile("global_store_dword %0, %1, off sc0 sc1"
                   :: "v"(gslots + wg), "v"(tv) : "memory");
    }

    mfma_regs(1, ah, al, scr2);

    float ngxr = 0.f, ngxu = 0.f, ngxc = 0.f;
    if (own && t + 1 < TT) {
      const int tgn = dir ? (TT - 2 - t) : (t + 1);
      const float* row = gx + ((size_t)tgn * 64 + b0 + ob) * 1536 + hs + oj;
      ngxr = row[0]; ngxu = row[512]; ngxc = row[1024];
    }

    poll(2 * t + 1);

    load_frags(rPkG, ah, al, false, nullptr);
    mfma_regs(2, ah, al, scr);
    __syncthreads();

    float hn = 0.f;
    unsigned short hh_ = 0, ll_ = 0;
    if (own) {
      float upre = scr2[0][ob][oj] + scr2[1][ob][oj] + scr2[2][ob][oj] + scr2[3][ob][oj] + gxu;
      float uv = sigm(upre);
      float cpre = scr[0][ob][oj] + scr[1][ob][oj] + scr[2][ob][oj] + scr[3][ob][oj] + gxc;
      float cv = tanh_fast(cpre);
      hn = uv * hv + (1.f - uv) * cv;
      hh_ = f2bfu(hn);
      ll_ = f2bfu(hn - bfu2f(hh_));
    }

    if (t == TT - 1) {
      if (own) {
        if (yHi) {
          const int ycol = (NB == 16) ? (dir * 512 + hs + oj) : (hs + oj);
          const size_t yi = ((size_t)tg * 64 + (b0 + ob)) * yld + ycol;
          yHi[yi] = hh_; yLo[yi] = ll_;
        }
        if (outb) outb[((size_t)(b0 + ob) * TT + t) * 512 + hs + oj] = hn;
        if (stout) stout[(size_t)(b0 + ob) * 512 + hs + oj] = hn;
      }
      break;
    }

    if (own) {
      unsigned e = (unsigned)hh_ | ((unsigned)ll_ << 16);
      asm volatile("global_store_dword %0, %1, off sc0 sc1"
                   :: "v"(hPkG + tileo + ui), "v"(e) : "memory");
    }
    vm_drain();
    __syncthreads();
    if (tid == 0) {
      unsigned tv = 2 * t + 2;
      asm volatile("global_store_dword %0, %1, off sc0 sc1"
                   :: "v"(gslots + wg), "v"(tv) : "memory");
    }

    if (own) {
      if (yHi) {
        const int ycol = (NB == 16) ? (dir * 512 + hs + oj) : (hs + oj);
        const size_t yi = ((size_t)tg * 64 + (b0 + ob)) * yld + ycol;
        yHi[yi] = hh_; yLo[yi] = ll_;
      }
      if (outb) outb[((size_t)(b0 + ob) * TT + t) * 512 + hs + oj] = hn;
    }
    gxr = ngxr; gxu = ngxu; gxc = ngxc;

    poll(2 * t + 2);
  }
}

// ------------------------------------------------------- fused u1+u2 scan
// 256 WGs: bid<128 -> u1 (4 groups x 32, batches g*16..), bid>=128 -> u2.
// u1: gx from precomputed bufA; emits y1 hi/lo (sc1) BEFORE its h'-flag so
// the flag also publishes y1. u2: polls u1's flags, computes x-proj on the
// fly (A = y1 planes, B = packed x-part weights from L2), then normal step.
__global__ __launch_bounds__(256, 1) void uni_fused_kernel(
    const float* __restrict__ gx1,
    const unsigned short* __restrict__ w1Hi, const unsigned short* __restrict__ w1Lo,
    const unsigned short* __restrict__ w2Hi, const unsigned short* __restrict__ w2Lo,
    const float* __restrict__ bg2, const float* __restrict__ bc2,
    unsigned* __restrict__ hPk1, unsigned* __restrict__ rPk1,
    unsigned* __restrict__ hPk2, unsigned* __restrict__ rPk2,
    unsigned* __restrict__ slots1, unsigned* __restrict__ slots2,
    unsigned short* __restrict__ y1Hi, unsigned short* __restrict__ y1Lo,
    float* __restrict__ out, float* __restrict__ st1, float* __restrict__ st2) {
  __shared__ unsigned short wHi_s[3 * 8192];
  __shared__ unsigned short wLo_s[3 * 8192];
  __shared__ float scr[4][16][17];
  __shared__ float scr2[4][16][17];
  __shared__ float scr3[4][16][17];

  const int tid = threadIdx.x;
  const int lane = tid & 63;
  const int wv = tid >> 6;
  const int bid = blockIdx.x;
  const int role = (bid >= 128);          // 0 = u1, 1 = u2
  const int g = (bid & 127) >> 5;         // 0..3
  const int wg = bid & 31;
  const int hs = wg << 4;
  const int b0 = g * 16;

  const unsigned short* wph = role ? w2Hi : w1Hi;
  const unsigned short* wpl = role ? w2Lo : w1Lo;
  const int ktTot = role ? 32 : 48;
  const int ktH0 = role ? 16 : 32;
  unsigned* hPk = role ? hPk2 : hPk1;
  unsigned* rPk = role ? rPk2 : rPk1;
  unsigned* myslots = (role ? slots2 : slots1) + g * 32;
  unsigned* u1gs = slots1 + g * 32;

  {  // stationary h-part weights -> LDS
    const int nt0[3] = {wg, 32 + wg, 64 + wg};
    for (int c = 0; c < 3; ++c) {
      const unsigned short* sH = wph + ((size_t)nt0[c] * ktTot + ktH0) * 512;
      const unsigned short* sL = wpl + ((size_t)nt0[c] * ktTot + ktH0) * 512;
      unsigned short* dH = wHi_s + c * 8192;
      unsigned short* dL = wLo_s + c * 8192;
#pragma unroll
      for (int it = 0; it < 4; ++it) {
        const int o = (it * 256 + tid) * 8;
        *(s16x8*)(dH + o) = *(const s16x8*)(sH + o);
        *(s16x8*)(dL + o) = *(const s16x8*)(sL + o);
      }
    }
  }
  __syncthreads();

  const int fm = lane & 15;
  const int fkg = lane >> 4;
  const int afe = fm * 512;
  const int asw = (fm & 7) << 3;
  const int ob = tid >> 4, oj = tid & 15;
  const int ui = ob * 512 + ((hs + oj) ^ ((ob & 7) << 3));
  const size_t tileo = (size_t)g * 8192;

  auto mfma_regs = [&](int cidx, const s16x8* ah, const s16x8* al,
                       float (*dst)[16][17]) {
    f32x4 acc0 = {0.f, 0.f, 0.f, 0.f}, acc1 = {0.f, 0.f, 0.f, 0.f};
#pragma unroll
    for (int q = 0; q < 4; ++q) {
      const int kt = wv * 4 + q;
      const int wo = ((cidx * 16 + kt) * 64 + lane) * 8;
      s16x8 bh = *(const s16x8*)(wHi_s + wo);
      s16x8 bl = *(const s16x8*)(wLo_s + wo);
      if (q & 1) {
        acc1 = __builtin_amdgcn_mfma_f32_16x16x32_bf16(ah[q], bh, acc1, 0, 0, 0);
        acc1 = __builtin_amdgcn_mfma_f32_16x16x32_bf16(ah[q], bl, acc1, 0, 0, 0);
        acc1 = __builtin_amdgcn_mfma_f32_16x16x32_bf16(al[q], bh, acc1, 0, 0, 0);
      } else {
        acc0 = __builtin_amdgcn_mfma_f32_16x16x32_bf16(ah[q], bh, acc0, 0, 0, 0);
        acc0 = __builtin_amdgcn_mfma_f32_16x16x32_bf16(ah[q], bl, acc0, 0, 0, 0);
        acc0 = __builtin_amdgcn_mfma_f32_16x16x32_bf16(al[q], bh, acc0, 0, 0, 0);
      }
    }
#pragma unroll
    for (int j = 0; j < 4; ++j) dst[wv][fkg * 4 + j][fm] = acc0[j] + acc1[j];
  };

  // x-proj MFMA: B fragments streamed from the global pack (x-part kt 0..15)
  auto mfma_xp = [&](int cidx, const s16x8* ah, const s16x8* al,
                     float (*dst)[16][17]) {
    const int nt0[3] = {wg, 32 + wg, 64 + wg};
    f32x4 acc0 = {0.f, 0.f, 0.f, 0.f}, acc1 = {0.f, 0.f, 0.f, 0.f};
#pragma unroll
    for (int q = 0; q < 4; ++q) {
      const int kt = wv * 4 + q;
      const size_t bo = ((size_t)nt0[cidx] * 32 + kt) * 512 + lane * 8;
      s16x8 bh = *(const s16x8*)(w2Hi + bo);
      s16x8 bl = *(const s16x8*)(w2Lo + bo);
      if (q & 1) {
        acc1 = __builtin_amdgcn_mfma_f32_16x16x32_bf16(ah[q], bh, acc1, 0, 0, 0);
        acc1 = __builtin_amdgcn_mfma_f32_16x16x32_bf16(ah[q], bl, acc1, 0, 0, 0);
        acc1 = __builtin_amdgcn_mfma_f32_16x16x32_bf16(al[q], bh, acc1, 0, 0, 0);
      } else {
        acc0 = __builtin_amdgcn_mfma_f32_16x16x32_bf16(ah[q], bh, acc0, 0, 0, 0);
        acc0 = __builtin_amdgcn_mfma_f32_16x16x32_bf16(ah[q], bl, acc0, 0, 0, 0);
        acc0 = __builtin_amdgcn_mfma_f32_16x16x32_bf16(al[q], bh, acc0, 0, 0, 0);
      }
    }
#pragma unroll
    for (int j = 0; j < 4; ++j) dst[wv][fkg * 4 + j][fm] = acc0[j] + acc1[j];
  };

  auto load_frags = [&](const unsigned* pk, s16x8* ah, s16x8* al,
                        bool withHv, unsigned* hvOut) {
    u32x4 d[4][2];
#pragma unroll
    for (int q = 0; q < 4; ++q) {
      const int kt = wv * 4 + q;
      const unsigned* p = pk + tileo + afe + ((kt * 32 + fkg * 8) ^ asw);
      asm volatile("global_load_dwordx4 %0, %1, off sc0 sc1"
                   : "=v"(d[q][0]) : "v"(p) : "memory");
      asm volatile("global_load_dwordx4 %0, %1, off sc0 sc1"
                   : "=v"(d[q][1]) : "v"(p + 4) : "memory");
    }
    if (withHv)
      asm volatile("global_load_dword %0, %1, off sc0 sc1"
                   : "=v"(*hvOut) : "v"(pk + tileo + ui) : "memory");
    vm_drain();
    __builtin_amdgcn_sched_barrier(0);
#pragma unroll
    for (int q = 0; q < 4; ++q) {
      u32x4 hh, ll;
#pragma unroll
      for (int i = 0; i < 2; ++i) {
        const u32x4 dd = d[q][i];
        hh[2 * i] = (dd[0] & 0xffffu) | (dd[1] << 16);
        hh[2 * i + 1] = (dd[2] & 0xffffu) | (dd[3] << 16);
        ll[2 * i] = (dd[0] >> 16) | (dd[1] & 0xffff0000u);
        ll[2 * i + 1] = (dd[2] >> 16) | (dd[3] & 0xffff0000u);
      }
      __builtin_memcpy(&ah[q], &hh, 16);
      __builtin_memcpy(&al[q], &ll, 16);
    }
  };

  auto poll_arr = [&](const unsigned* arr, unsigned target) {
    if (tid < 32) {
      const unsigned* p = arr + tid;
      unsigned v;
      do {
        asm volatile("global_load_dword %0, %1, off sc0 sc1\n\ts_waitcnt vmcnt(0)"
                     : "=v"(v) : "v"(p) : "memory");
      } while (!__all(v >= target));
    }
    __syncthreads();
  };

  if (role == 0) {
    // ------------------------------ U1 ------------------------------
    float gxr, gxu, gxc;
    {
      const float* row = gx1 + ((size_t)0 * 64 + b0 + ob) * 1536 + hs + oj;
      gxr = row[0]; gxu = row[512]; gxc = row[1024];
    }
    for (int t = 0; t < TT; ++t) {
      s16x8 ah[4], al[4];
      unsigned hvu = 0;
      load_frags(hPk, ah, al, true, &hvu);
      mfma_regs(0, ah, al, scr);
      __syncthreads();

      float rpre = scr[0][ob][oj] + scr[1][ob][oj] + scr[2][ob][oj] + scr[3][ob][oj] + gxr;
      float sg = sigm(rpre);
      float hv = bfu2f((unsigned short)(hvu & 0xffffu)) + bfu2f((unsigned short)(hvu >> 16));
      float rh = sg * hv;
      {
        unsigned short hh_ = f2bfu(rh);
        unsigned short ll_ = f2bfu(rh - bfu2f(hh_));
        unsigned e = (unsigned)hh_ | ((unsigned)ll_ << 16);
        asm volatile("global_store_dword %0, %1, off sc0 sc1"
                     :: "v"(rPk + tileo + ui), "v"(e) : "memory");
      }
      vm_drain();
      __syncthreads();
      if (tid == 0) {
        unsigned tv = 2 * t + 1;
        asm volatile("global_store_dword %0, %1, off sc0 sc1"
                     :: "v"(myslots + wg), "v"(tv) : "memory");
      }

      mfma_regs(1, ah, al, scr2);

      float ngxr = 0.f, ngxu = 0.f, ngxc = 0.f;
      if (t + 1 < TT) {
        const float* row = gx1 + ((size_t)(t + 1) * 64 + b0 + ob) * 1536 + hs + oj;
        ngxr = row[0]; ngxu = row[512]; ngxc = row[1024];
      }

      poll_arr(myslots, 2 * t + 1);

      load_frags(rPk, ah, al, false, nullptr);
      mfma_regs(2, ah, al, scr);
      __syncthreads();

      float upre = scr2[0][ob][oj] + scr2[1][ob][oj] + scr2[2][ob][oj] + scr2[3][ob][oj] + gxu;
      float uv = sigm(upre);
      float cpre = scr[0][ob][oj] + scr[1][ob][oj] + scr[2][ob][oj] + scr[3][ob][oj] + gxc;
      float hn = uv * hv + (1.f - uv) * tanh_fast(cpre);
      unsigned short hh_ = f2bfu(hn);
      unsigned short ll_ = f2bfu(hn - bfu2f(hh_));

      // y1 (sc1) BEFORE the drain so flag 2t+2 publishes it for u2
      {
        const size_t yi = ((size_t)t * 64 + (b0 + ob)) * 512 + hs + oj;
        sc1_store_b16(y1Hi + yi, hh_);
        sc1_store_b16(y1Lo + yi, ll_);
      }
      if (t < TT - 1) {
        unsigned e = (unsigned)hh_ | ((unsigned)ll_ << 16);
        asm volatile("global_store_dword %0, %1, off sc0 sc1"
                     :: "v"(hPk + tileo + ui), "v"(e) : "memory");
      } else {
        st1[(size_t)(b0 + ob) * 512 + hs + oj] = hn;
      }
      vm_drain();
      __syncthreads();
      if (tid == 0) {
        unsigned tv = 2 * t + 2;
        asm volatile("global_store_dword %0, %1, off sc0 sc1"
                     :: "v"(myslots + wg), "v"(tv) : "memory");
      }
      if (t == TT - 1) break;
      gxr = ngxr; gxu = ngxu; gxc = ngxc;
      poll_arr(myslots, 2 * t + 2);
    }
  } else {
    // ------------------------------ U2 ------------------------------
    const float br = bg2[hs + oj], bu = bg2[512 + hs + oj], bc_ = bc2[hs + oj];
    for (int t = 0; t < TT; ++t) {
      // wait for y1(t) from u1 group g
      poll_arr(u1gs, 2 * t + 2);

      // x-projection: A = y1(t) planes, B = x-part pack (kt 0..15)
      s16x8 xh[4], xl[4];
      {
#pragma unroll
        for (int q = 0; q < 4; ++q) {
          const int kt = wv * 4 + q;
          const size_t yo = ((size_t)t * 64 + b0 + fm) * 512 + kt * 32 + fkg * 8;
          asm volatile("global_load_dwordx4 %0, %1, off sc0 sc1"
                       : "=v"(xh[q]) : "v"(y1Hi + yo) : "memory");
          asm volatile("global_load_dwordx4 %0, %1, off sc0 sc1"
                       : "=v"(xl[q]) : "v"(y1Lo + yo) : "memory");
        }
        vm_drain();
        __builtin_amdgcn_sched_barrier(0);
      }
      mfma_xp(0, xh, xl, scr);
      mfma_xp(1, xh, xl, scr2);
      mfma_xp(2, xh, xl, scr3);
      __syncthreads();
      float gxr = scr[0][ob][oj] + scr[1][ob][oj] + scr[2][ob][oj] + scr[3][ob][oj] + br;
      float gxu = scr2[0][ob][oj] + scr2[1][ob][oj] + scr2[2][ob][oj] + scr2[3][ob][oj] + bu;
      float gxc = scr3[0][ob][oj] + scr3[1][ob][oj] + scr3[2][ob][oj] + scr3[3][ob][oj] + bc_;
      __syncthreads();

      // recurrent phase 1
      s16x8 ah[4], al[4];
      unsigned hvu = 0;
      load_frags(hPk, ah, al, true, &hvu);
      mfma_regs(0, ah, al, scr);
      __syncthreads();

      float rpre = scr[0][ob][oj] + scr[1][ob][oj] + scr[2][ob][oj] + scr[3][ob][oj] + gxr;
      float sg = sigm(rpre);
      float hv = bfu2f((unsigned short)(hvu & 0xffffu)) + bfu2f((unsigned short)(hvu >> 16));
      float rh = sg * hv;
      {
        unsigned short hh_ = f2bfu(rh);
        unsigned short ll_ = f2bfu(rh - bfu2f(hh_));
        unsigned e = (unsigned)hh_ | ((unsigned)ll_ << 16);
        asm volatile("global_store_dword %0, %1, off sc0 sc1"
                     :: "v"(rPk + tileo + ui), "v"(e) : "memory");
      }
      vm_drain();
      __syncthreads();
      if (tid == 0) {
        unsigned tv = 2 * t + 1;
        asm volatile("global_store_dword %0, %1, off sc0 sc1"
                     :: "v"(myslots + wg), "v"(tv) : "memory");
      }

      mfma_regs(1, ah, al, scr2);
      poll_arr(myslots, 2 * t + 1);

      load_frags(rPk, ah, al, false, nullptr);
      mfma_regs(2, ah, al, scr);
      __syncthreads();

      float upre = scr2[0][ob][oj] + scr2[1][ob][oj] + scr2[2][ob][oj] + scr2[3][ob][oj] + gxu;
      float uv = sigm(upre);
      float cpre = scr[0][ob][oj] + scr[1][ob][oj] + scr[2][ob][oj] + scr[3][ob][oj] + gxc;
      float hn = uv * hv + (1.f - uv) * tanh_fast(cpre);

      if (t == TT - 1) {
        out[((size_t)(b0 + ob) * TT + t) * 512 + hs + oj] = hn;
        st2[(size_t)(b0 + ob) * 512 + hs + oj] = hn;
        break;
      }
      {
        unsigned short hh_ = f2bfu(hn);
        unsigned short ll_ = f2bfu(hn - bfu2f(hh_));
        unsigned e = (unsigned)hh_ | ((unsigned)ll_ << 16);
        asm volatile("global_store_dword %0, %1, off sc0 sc1"
                     :: "v"(hPk + tileo + ui), "v"(e) : "memory");
      }
      vm_drain();
      __syncthreads();
      if (tid == 0) {
        unsigned tv = 2 * t + 2;
        asm volatile("global_store_dword %0, %1, off sc0 sc1"
                     :: "v"(myslots + wg), "v"(tv) : "memory");
      }
      out[((size_t)(b0 + ob) * TT + t) * 512 + hs + oj] = hn;   // covers poll
      poll_arr(myslots, 2 * t + 2);
    }
  }
}

// ---------------------------------------------------------------- launcher
extern "C" void kernel_launch(void* const* d_in, const int* in_sizes, int n_in,
                              void* d_out, int out_size, void* d_ws, size_t ws_size,
                              hipStream_t stream) {
  (void)in_sizes; (void)n_in; (void)out_size; (void)ws_size;
  const int* x = (const int*)d_in[0];
  const float* emb = (const float*)d_in[1];
  const float* WgFw = (const float*)d_in[2];
  const float* bgFw = (const float*)d_in[3];
  const float* WcFw = (const float*)d_in[4];
  const float* bcFw = (const float*)d_in[5];
  const float* WgBw = (const float*)d_in[6];
  const float* bgBw = (const float*)d_in[7];
  const float* WcBw = (const float*)d_in[8];
  const float* bcBw = (const float*)d_in[9];
  const float* WgU1 = (const float*)d_in[10];
  const float* bgU1 = (const float*)d_in[11];
  const float* WcU1 = (const float*)d_in[12];
  const float* bcU1 = (const float*)d_in[13];
  const float* WgU2 = (const float*)d_in[14];
  const float* bgU2 = (const float*)d_in[15];
  const float* WcU2 = (const float*)d_in[16];
  const float* bcU2 = (const float*)d_in[17];

  char* ws = (char*)d_ws;
  float* bufA = (float*)(ws + 0);                    // 39,321,600
  float* bufB = (float*)(ws + 39321600);             // 39,321,600
  unsigned short* ycatHi = (unsigned short*)(ws + 78643200);   // 13,107,200
  unsigned short* ycatLo = (unsigned short*)(ws + 91750400);   // 13,107,200
  unsigned short* y1Hi = (unsigned short*)(ws + 78643200);     // overlay (ycat dead)
  unsigned short* y1Lo = (unsigned short*)(ws + 85196800);
  unsigned short* wpFwHi = (unsigned short*)(ws + 104857600);  // 3,145,728 each
  unsigned short* wpFwLo = (unsigned short*)(ws + 108003328);
  unsigned short* wpBwHi = (unsigned short*)(ws + 111149056);
  unsigned short* wpBwLo = (unsigned short*)(ws + 114294784);
  unsigned short* wpU1Hi = (unsigned short*)(ws + 117440512);  // 4,718,592 each
  unsigned short* wpU1Lo = (unsigned short*)(ws + 122159104);
  unsigned short* wpU2Hi = (unsigned short*)(ws + 104857600);  // overlay wpFw AFTER bidir scan
  unsigned short* wpU2Lo = (unsigned short*)(ws + 108003328);
  unsigned* tiles = (unsigned*)(ws + 126877696);     // 524,288 B
  unsigned* bars = (unsigned*)(ws + 127401984);      // 4,096 B

  unsigned* hPkB = tiles;               // bidir: 262,144 B (8 groups)
  unsigned* rPkB = tiles + 65536;
  unsigned* hPk1 = tiles;               // fused: 4 x 131,072 B (4 groups each)
  unsigned* rPk1 = tiles + 32768;
  unsigned* hPk2 = tiles + 65536;
  unsigned* rPk2 = tiles + 98304;

  float* out = (float*)d_out;
  float* st1 = out + (size_t)64 * TT * 512;
  float* st2 = st1 + 64 * 512;

  hipMemsetAsync(bars, 0, 4096, stream);

  pack_w_kernel<<<768, 256, 0, stream>>>(WgFw, WcFw, 1024, 512, 32, wpFwHi, wpFwLo);
  pack_w_kernel<<<768, 256, 0, stream>>>(WgBw, WcBw, 1024, 512, 32, wpBwHi, wpBwLo);
  pack_w_kernel<<<1152, 256, 0, stream>>>(WgU1, WcU1, 1024, 512, 48, wpU1Hi, wpU1Lo);

  gemm_mfma<0><<<dim3(50, 12), 256, 0, stream>>>(
      x, emb, nullptr, nullptr, 0, wpFwHi, wpFwLo, 32, 16, bgFw, bcFw, bufA);
  gemm_mfma<0><<<dim3(50, 12), 256, 0, stream>>>(
      x, emb, nullptr, nullptr, 0, wpBwHi, wpBwLo, 32, 16, bgBw, bcBw, bufB);

  hipMemsetAsync(tiles, 0, 524288, stream);
  {  // bidirectional scan -> ycat planes
    const float *a0 = bufA, *a1 = bufB;
    const unsigned short *w0 = wpFwHi, *w1 = wpFwLo, *w2 = wpBwHi, *w3 = wpBwLo;
    int ktT = 32, ktH = 16;
    unsigned *h0 = hPkB, *r0 = rPkB;
    unsigned* bp = bars;
    unsigned short *yh = ycatHi, *yl = ycatLo; int yld = 1024;
    float *on = nullptr, *sn = nullptr;
    void* args[] = {&a0, &a1, &w0, &w1, &w2, &w3, &ktT, &ktH, &h0, &r0,
                    &bp, &yh, &yl, &yld, &on, &sn};
    hipLaunchCooperativeKernel((const void*)gru_scan_kernel<16>, dim3(256), dim3(256),
                               args, 0, stream);
  }

  // u2 pack overlays wpFw (bidir scan done with those weights)
  pack_w_kernel<<<768, 256, 0, stream>>>(WgU2, WcU2, 1024, 512, 32, wpU2Hi, wpU2Lo);

  // u1 input projections: A = ycat planes [6400][1024]
  gemm_mfma<1><<<dim3(50, 12), 256, 0, stream>>>(
      nullptr, nullptr, ycatHi, ycatLo, 1024, wpU1Hi, wpU1Lo, 48, 32, bgU1, bcU1, bufA);

  hipMemsetAsync(tiles, 0, 524288, stream);
  {  // fused u1 + u2 scan
    const float* a0 = bufA;
    const unsigned short *w0 = wpU1Hi, *w1 = wpU1Lo, *w2 = wpU2Hi, *w3 = wpU2Lo;
    const float *b2 = bgU2, *c2 = bcU2;
    unsigned *h1 = hPk1, *r1 = rPk1, *h2 = hPk2, *r2 = rPk2;
    unsigned *s1p = bars + 256, *s2p = bars + 384;
    unsigned short *yh = y1Hi, *yl = y1Lo;
    float *op = out, *t1 = st1, *t2 = st2;
    void* args[] = {&a0, &w0, &w1, &w2, &w3, &b2, &c2,
                    &h1, &r1, &h2, &r2, &s1p, &s2p, &yh, &yl, &op, &t1, &t2};
    hipLaunchCooperativeKernel((const void*)uni_fused_kernel, dim3(256), dim3(256),
                               args, 0, stream);
  }
}

// Round 13
// 1545.321 us; speedup vs baseline: 1.1713x; 1.0295x over previous
//
#include <hip/hip_runtime.h>
#include <hip/hip_bf16.h>

// GRU encoder: B=64, T=100, E=512, U=512.
// d_out = FLOAT32: output [B,T,U] then states [2,B,U].
// Bidir scan: embedding + x-projection fused on the fly (xp hidden in
// exchange-latency windows). Fused u1+u2: u2's xp moved into its r/h windows.
// Exchange protocol = proven r10 (packed-u32 sc1 + monotonic flags).

#define TT 100

using f32x4 = __attribute__((ext_vector_type(4))) float;
using s16x8 = __attribute__((ext_vector_type(8))) short;
using u32x4 = __attribute__((ext_vector_type(4))) unsigned;

__device__ __forceinline__ unsigned short f2bfu(float x) {
  __hip_bfloat16 b = __float2bfloat16(x);
  unsigned short u;
  __builtin_memcpy(&u, &b, sizeof(u));
  return u;
}
__device__ __forceinline__ float bfu2f(unsigned short u) {
  __hip_bfloat16 b;
  __builtin_memcpy(&b, &u, sizeof(b));
  return __bfloat162float(b);
}
__device__ __forceinline__ float sigm(float x) {
  x = fminf(fmaxf(x, -30.f), 30.f);
  return 1.f / (1.f + __expf(-x));
}
__device__ __forceinline__ float tanh_fast(float x) {
  x = fminf(fmaxf(x, -15.f), 15.f);
  float e = __expf(-2.f * x);
  return (1.f - e) / (1.f + e);
}
__device__ __forceinline__ void vm_drain() {
  asm volatile("s_waitcnt vmcnt(0)" ::: "memory");
}
__device__ __forceinline__ void sc1_store_b16(void* p, unsigned v) {
  asm volatile("global_store_short %0, %1, off sc0 sc1" :: "v"(p), "v"(v) : "memory");
}

// ------------------------------------------------- pack weights (full K)
// [nt 0..95][kt 0..ktTot-1][lane 0..63][elem 0..7], hi/lo.
__global__ __launch_bounds__(256) void pack_w_kernel(const float* __restrict__ Wg,
                                                     const float* __restrict__ Wc,
                                                     int ldg, int ldc, int ktTot,
                                                     unsigned short* __restrict__ hi,
                                                     unsigned short* __restrict__ lo) {
  const int gg = blockIdx.x * 256 + threadIdx.x;
  if (gg >= 96 * ktTot * 64) return;
  const int lane = gg & 63;
  const int pair = gg >> 6;
  const int kt = pair % ktTot;
  const int nt = pair / ktTot;
  const int kg = lane >> 4;
  const int nl = lane & 15;
  const size_t off = (size_t)gg * 8;
  for (int i = 0; i < 8; ++i) {
    const int k = kt * 32 + kg * 8 + i;
    float v = (nt < 64) ? Wg[(size_t)k * ldg + nt * 16 + nl]
                        : Wc[(size_t)k * ldc + (nt - 64) * 16 + nl];
    unsigned short h = f2bfu(v);
    hi[off + i] = h;
    lo[off + i] = f2bfu(v - bfu2f(h));
  }
}

// --------------------------------------------- split-bf16 MFMA input GEMM
// Only the ASRC=1 (hi/lo plane input) variant is launched (u1 projections).
template <int ASRC>
__global__ __launch_bounds__(256) void gemm_mfma(
    const int* __restrict__ xtok, const float* __restrict__ emb,
    const unsigned short* __restrict__ aHi, const unsigned short* __restrict__ aLo, int lda,
    const unsigned short* __restrict__ bHi, const unsigned short* __restrict__ bLo,
    int ktTot, int ktX,
    const float* __restrict__ bg, const float* __restrict__ bc,
    float* __restrict__ C) {
  __shared__ unsigned short Ah[128 * 40];
  __shared__ unsigned short Al[128 * 40];

  const int tid = threadIdx.x;
  const int lane = tid & 63;
  const int w = tid >> 6;
  const int bm = blockIdx.x, bn = blockIdx.y;
  const int fm = lane & 15, fkg = lane >> 4;

  const int arow = tid >> 1;
  const int koff = (tid & 1) * 16;
  const int rowg = bm * 128 + arow;

  f32x4 acc[2][8];
#pragma unroll
  for (int rt = 0; rt < 2; ++rt)
#pragma unroll
    for (int ni = 0; ni < 8; ++ni) acc[rt][ni] = (f32x4){0.f, 0.f, 0.f, 0.f};

  for (int kt = 0; kt < ktX; ++kt) {
    __syncthreads();
    {
      const size_t so = (size_t)rowg * lda + kt * 32 + koff;
      s16x8 h0 = *(const s16x8*)(aHi + so);
      s16x8 h1 = *(const s16x8*)(aHi + so + 8);
      s16x8 l0 = *(const s16x8*)(aLo + so);
      s16x8 l1 = *(const s16x8*)(aLo + so + 8);
      *(s16x8*)(Ah + arow * 40 + koff) = h0;
      *(s16x8*)(Ah + arow * 40 + koff + 8) = h1;
      *(s16x8*)(Al + arow * 40 + koff) = l0;
      *(s16x8*)(Al + arow * 40 + koff + 8) = l1;
    }
    __syncthreads();

    s16x8 ah[2], al[2];
#pragma unroll
    for (int rt = 0; rt < 2; ++rt) {
      const int m = w * 32 + rt * 16 + fm;
      ah[rt] = *(const s16x8*)(Ah + m * 40 + fkg * 8);
      al[rt] = *(const s16x8*)(Al + m * 40 + fkg * 8);
    }
#pragma unroll
    for (int ni = 0; ni < 8; ++ni) {
      const int nt = bn * 8 + ni;
      const size_t bo = ((size_t)nt * ktTot + kt) * 512 + lane * 8;
      s16x8 bh = *(const s16x8*)(bHi + bo);
      s16x8 bl = *(const s16x8*)(bLo + bo);
#pragma unroll
      for (int rt = 0; rt < 2; ++rt) {
        acc[rt][ni] = __builtin_amdgcn_mfma_f32_16x16x32_bf16(ah[rt], bh, acc[rt][ni], 0, 0, 0);
        acc[rt][ni] = __builtin_amdgcn_mfma_f32_16x16x32_bf16(ah[rt], bl, acc[rt][ni], 0, 0, 0);
        acc[rt][ni] = __builtin_amdgcn_mfma_f32_16x16x32_bf16(al[rt], bh, acc[rt][ni], 0, 0, 0);
      }
    }
  }

#pragma unroll
  for (int ni = 0; ni < 8; ++ni) {
    const int nt = bn * 8 + ni;
    int dcol; float bias;
    if (nt < 64) { dcol = nt * 16 + fm; bias = bg[dcol]; }
    else { dcol = 1024 + (nt - 64) * 16 + fm; bias = bc[(nt - 64) * 16 + fm]; }
#pragma unroll
    for (int rt = 0; rt < 2; ++rt)
#pragma unroll
      for (int j = 0; j < 4; ++j) {
        const int row = bm * 128 + w * 32 + rt * 16 + fkg * 4 + j;
        C[(size_t)row * 1536 + dcol] = acc[rt][ni][j] + bias;
      }
  }
}

// --------------------------------------------------- bidir scan (fused xp)
// 8 groups x 32 WGs; group g: dir = g&1, batches (g>>1)*16.. . Per step the
// x-projection for step t+1 (A = embedding gather, B = x-part pack kt 0..15)
// is computed inside the two exchange-latency windows.
__global__ __launch_bounds__(256, 1) void bidir_scan_kernel(
    const int* __restrict__ xtok, const float* __restrict__ emb,
    const unsigned short* __restrict__ wHiF, const unsigned short* __restrict__ wLoF,
    const unsigned short* __restrict__ wHiB, const unsigned short* __restrict__ wLoB,
    const float* __restrict__ bgF, const float* __restrict__ bcF,
    const float* __restrict__ bgB, const float* __restrict__ bcB,
    unsigned* __restrict__ hPkG, unsigned* __restrict__ rPkG,
    unsigned* __restrict__ slots,
    unsigned short* __restrict__ yHi, unsigned short* __restrict__ yLo) {
  __shared__ unsigned short wHi_s[3 * 8192];
  __shared__ unsigned short wLo_s[3 * 8192];
  __shared__ float scr[4][16][17];
  __shared__ float scr2[4][16][17];
  __shared__ float scr3[4][16][17];

  const int tid = threadIdx.x;
  const int lane = tid & 63;
  const int wv = tid >> 6;
  const int bid = blockIdx.x;
  const int g = bid & 7;
  const int wg = bid >> 3;
  const int hs = wg << 4;
  const int dir = g & 1;
  const int b0 = (g >> 1) << 4;

  const unsigned short* wph = dir ? wHiB : wHiF;
  const unsigned short* wpl = dir ? wLoB : wLoF;
  const float* bgD = dir ? bgB : bgF;
  const float* bcD = dir ? bcB : bcF;

  {  // stationary h-part weights (kt 16..31 of ktTot=32) -> LDS
    const int nt0[3] = {wg, 32 + wg, 64 + wg};
    for (int c = 0; c < 3; ++c) {
      const unsigned short* sH = wph + ((size_t)nt0[c] * 32 + 16) * 512;
      const unsigned short* sL = wpl + ((size_t)nt0[c] * 32 + 16) * 512;
      unsigned short* dH = wHi_s + c * 8192;
      unsigned short* dL = wLo_s + c * 8192;
#pragma unroll
      for (int it = 0; it < 4; ++it) {
        const int o = (it * 256 + tid) * 8;
        *(s16x8*)(dH + o) = *(const s16x8*)(sH + o);
        *(s16x8*)(dL + o) = *(const s16x8*)(sL + o);
      }
    }
  }
  __syncthreads();

  unsigned* gslots = slots + g * 32;
  const int fm = lane & 15;
  const int fkg = lane >> 4;
  const int afe = fm * 512;
  const int asw = (fm & 7) << 3;
  const int ob = tid >> 4, oj = tid & 15;
  const int ui = ob * 512 + ((hs + oj) ^ ((ob & 7) << 3));
  const size_t tileo = (size_t)g * 8192;
  const float br = bgD[hs + oj], bu = bgD[512 + hs + oj], bcv = bcD[hs + oj];

  auto mfma_regs = [&](int cidx, const s16x8* ah, const s16x8* al,
                       float (*dst)[16][17]) {
    f32x4 acc0 = {0.f, 0.f, 0.f, 0.f}, acc1 = {0.f, 0.f, 0.f, 0.f};
#pragma unroll
    for (int q = 0; q < 4; ++q) {
      const int kt = wv * 4 + q;
      const int wo = ((cidx * 16 + kt) * 64 + lane) * 8;
      s16x8 bh = *(const s16x8*)(wHi_s + wo);
      s16x8 bl = *(const s16x8*)(wLo_s + wo);
      if (q & 1) {
        acc1 = __builtin_amdgcn_mfma_f32_16x16x32_bf16(ah[q], bh, acc1, 0, 0, 0);
        acc1 = __builtin_amdgcn_mfma_f32_16x16x32_bf16(ah[q], bl, acc1, 0, 0, 0);
        acc1 = __builtin_amdgcn_mfma_f32_16x16x32_bf16(al[q], bh, acc1, 0, 0, 0);
      } else {
        acc0 = __builtin_amdgcn_mfma_f32_16x16x32_bf16(ah[q], bh, acc0, 0, 0, 0);
        acc0 = __builtin_amdgcn_mfma_f32_16x16x32_bf16(ah[q], bl, acc0, 0, 0, 0);
        acc0 = __builtin_amdgcn_mfma_f32_16x16x32_bf16(al[q], bh, acc0, 0, 0, 0);
      }
    }
#pragma unroll
    for (int j = 0; j < 4; ++j) dst[wv][fkg * 4 + j][fm] = acc0[j] + acc1[j];
  };

  // xp MFMA: B fragments streamed from global pack (x-part kt 0..15)
  auto mfma_xpg = [&](int nt, const s16x8* xh, const s16x8* xl,
                      float (*dst)[16][17]) {
    f32x4 acc0 = {0.f, 0.f, 0.f, 0.f}, acc1 = {0.f, 0.f, 0.f, 0.f};
#pragma unroll
    for (int q = 0; q < 4; ++q) {
      const int kt = wv * 4 + q;
      const size_t bo = ((size_t)nt * 32 + kt) * 512 + lane * 8;
      s16x8 bh = *(const s16x8*)(wph + bo);
      s16x8 bl = *(const s16x8*)(wpl + bo);
      if (q & 1) {
        acc1 = __builtin_amdgcn_mfma_f32_16x16x32_bf16(xh[q], bh, acc1, 0, 0, 0);
        acc1 = __builtin_amdgcn_mfma_f32_16x16x32_bf16(xh[q], bl, acc1, 0, 0, 0);
        acc1 = __builtin_amdgcn_mfma_f32_16x16x32_bf16(xl[q], bh, acc1, 0, 0, 0);
      } else {
        acc0 = __builtin_amdgcn_mfma_f32_16x16x32_bf16(xh[q], bh, acc0, 0, 0, 0);
        acc0 = __builtin_amdgcn_mfma_f32_16x16x32_bf16(xh[q], bl, acc0, 0, 0, 0);
        acc0 = __builtin_amdgcn_mfma_f32_16x16x32_bf16(xl[q], bh, acc0, 0, 0, 0);
      }
    }
#pragma unroll
    for (int j = 0; j < 4; ++j) dst[wv][fkg * 4 + j][fm] = acc0[j] + acc1[j];
  };

  // embedding A-fragment gather + split (lane's batch row = b0 + fm)
  auto load_emb_frags = [&](int tg, s16x8* xh, s16x8* xl) {
    const int tok = xtok[(b0 + fm) * TT + tg];
    const float* er = emb + (size_t)tok * 512;
#pragma unroll
    for (int q = 0; q < 4; ++q) {
      const int kt = wv * 4 + q;
      const float* p = er + kt * 32 + fkg * 8;
      f32x4 a = *(const f32x4*)p;
      f32x4 b = *(const f32x4*)(p + 4);
      s16x8 hh, ll;
#pragma unroll
      for (int j = 0; j < 4; ++j) {
        unsigned short h1 = f2bfu(a[j]);
        hh[j] = (short)h1; ll[j] = (short)f2bfu(a[j] - bfu2f(h1));
        unsigned short h2 = f2bfu(b[j]);
        hh[j + 4] = (short)h2; ll[j + 4] = (short)f2bfu(b[j] - bfu2f(h2));
      }
      xh[q] = hh; xl[q] = ll;
    }
  };

  auto load_frags = [&](const unsigned* pk, s16x8* ah, s16x8* al,
                        bool withHv, unsigned* hvOut) {
    u32x4 d[4][2];
#pragma unroll
    for (int q = 0; q < 4; ++q) {
      const int kt = wv * 4 + q;
      const unsigned* p = pk + tileo + afe + ((kt * 32 + fkg * 8) ^ asw);
      asm volatile("global_load_dwordx4 %0, %1, off sc0 sc1"
                   : "=v"(d[q][0]) : "v"(p) : "memory");
      asm volatile("global_load_dwordx4 %0, %1, off sc0 sc1"
                   : "=v"(d[q][1]) : "v"(p + 4) : "memory");
    }
    if (withHv)
      asm volatile("global_load_dword %0, %1, off sc0 sc1"
                   : "=v"(*hvOut) : "v"(pk + tileo + ui) : "memory");
    vm_drain();
    __builtin_amdgcn_sched_barrier(0);
#pragma unroll
    for (int q = 0; q < 4; ++q) {
      u32x4 hh, ll;
#pragma unroll
      for (int i = 0; i < 2; ++i) {
        const u32x4 dd = d[q][i];
        hh[2 * i] = (dd[0] & 0xffffu) | (dd[1] << 16);
        hh[2 * i + 1] = (dd[2] & 0xffffu) | (dd[3] << 16);
        ll[2 * i] = (dd[0] >> 16) | (dd[1] & 0xffff0000u);
        ll[2 * i + 1] = (dd[2] >> 16) | (dd[3] & 0xffff0000u);
      }
      __builtin_memcpy(&ah[q], &hh, 16);
      __builtin_memcpy(&al[q], &ll, 16);
    }
  };

  auto poll = [&](unsigned target) {
    if (tid < 32) {
      const unsigned* p = gslots + tid;
      unsigned v;
      do {
        asm volatile("global_load_dword %0, %1, off sc0 sc1\n\ts_waitcnt vmcnt(0)"
                     : "=v"(v) : "v"(p) : "memory");
      } while (!__all(v >= target));
    }
    __syncthreads();
  };

  // prologue: xp for step 0
  float gxr, gxu, gxc;
  {
    s16x8 xh0[4], xl0[4];
    load_emb_frags(dir ? TT - 1 : 0, xh0, xl0);
    mfma_xpg(wg, xh0, xl0, scr);
    mfma_xpg(32 + wg, xh0, xl0, scr2);
    mfma_xpg(64 + wg, xh0, xl0, scr3);
    __syncthreads();
    gxr = scr[0][ob][oj] + scr[1][ob][oj] + scr[2][ob][oj] + scr[3][ob][oj] + br;
    gxu = scr2[0][ob][oj] + scr2[1][ob][oj] + scr2[2][ob][oj] + scr2[3][ob][oj] + bu;
    gxc = scr3[0][ob][oj] + scr3[1][ob][oj] + scr3[2][ob][oj] + scr3[3][ob][oj] + bcv;
    __syncthreads();
  }

  s16x8 xh[4], xl[4];
  for (int t = 0; t < TT; ++t) {
    const int tg = dir ? (TT - 1 - t) : t;

    // ---- G1r ----
    s16x8 ah[4], al[4];
    unsigned hvu = 0;
    load_frags(hPkG, ah, al, true, &hvu);
    mfma_regs(0, ah, al, scr);
    __syncthreads();

    // ---- S1: sigmoid(r), store r*h ----
    float rpre = scr[0][ob][oj] + scr[1][ob][oj] + scr[2][ob][oj] + scr[3][ob][oj] + gxr;
    float sg = sigm(rpre);
    float hv = bfu2f((unsigned short)(hvu & 0xffffu)) + bfu2f((unsigned short)(hvu >> 16));
    float rh = sg * hv;
    {
      unsigned short hh_ = f2bfu(rh);
      unsigned short ll_ = f2bfu(rh - bfu2f(hh_));
      unsigned e = (unsigned)hh_ | ((unsigned)ll_ << 16);
      asm volatile("global_store_dword %0, %1, off sc0 sc1"
                   :: "v"(rPkG + tileo + ui), "v"(e) : "memory");
    }
    vm_drain();
    __syncthreads();
    if (tid == 0) {
      unsigned tv = 2 * t + 1;
      asm volatile("global_store_dword %0, %1, off sc0 sc1"
                   :: "v"(gslots + wg), "v"(tv) : "memory");
    }

    // ---- r-window: G1u + xp(u,c of t+1) ----
    mfma_regs(1, ah, al, scr2);
    float ngxr = 0.f, ngxu = 0.f, ngxc = 0.f;
    if (t + 1 < TT) {
      load_emb_frags(dir ? TT - 2 - t : t + 1, xh, xl);
      mfma_xpg(32 + wg, xh, xl, scr);     // scr dead after S1
      mfma_xpg(64 + wg, xh, xl, scr3);
      __syncthreads();
      ngxu = scr[0][ob][oj] + scr[1][ob][oj] + scr[2][ob][oj] + scr[3][ob][oj] + bu;
      ngxc = scr3[0][ob][oj] + scr3[1][ob][oj] + scr3[2][ob][oj] + scr3[3][ob][oj] + bcv;
      __syncthreads();
    }

    poll(2 * t + 1);

    // ---- G2 ----
    load_frags(rPkG, ah, al, false, nullptr);
    mfma_regs(2, ah, al, scr);
    __syncthreads();

    // ---- S2 ----
    float upre = scr2[0][ob][oj] + scr2[1][ob][oj] + scr2[2][ob][oj] + scr2[3][ob][oj] + gxu;
    float uv = sigm(upre);
    float cpre = scr[0][ob][oj] + scr[1][ob][oj] + scr[2][ob][oj] + scr[3][ob][oj] + gxc;
    float hn = uv * hv + (1.f - uv) * tanh_fast(cpre);
    unsigned short hh_ = f2bfu(hn);
    unsigned short ll_ = f2bfu(hn - bfu2f(hh_));

    if (t == TT - 1) {
      const size_t yi = ((size_t)tg * 64 + (b0 + ob)) * 1024 + dir * 512 + hs + oj;
      yHi[yi] = hh_; yLo[yi] = ll_;
      break;
    }

    {
      unsigned e = (unsigned)hh_ | ((unsigned)ll_ << 16);
      asm volatile("global_store_dword %0, %1, off sc0 sc1"
                   :: "v"(hPkG + tileo + ui), "v"(e) : "memory");
    }
    vm_drain();
    __syncthreads();
    if (tid == 0) {
      unsigned tv = 2 * t + 2;
      asm volatile("global_store_dword %0, %1, off sc0 sc1"
                   :: "v"(gslots + wg), "v"(tv) : "memory");
    }

    // ---- h-window: y-writes + xp(r of t+1) ----
    {
      const size_t yi = ((size_t)tg * 64 + (b0 + ob)) * 1024 + dir * 512 + hs + oj;
      yHi[yi] = hh_; yLo[yi] = ll_;
    }
    {
      mfma_xpg(wg, xh, xl, scr);          // scr dead after S2
      __syncthreads();
      ngxr = scr[0][ob][oj] + scr[1][ob][oj] + scr[2][ob][oj] + scr[3][ob][oj] + br;
    }
    gxr = ngxr; gxu = ngxu; gxc = ngxc;

    poll(2 * t + 2);                      // trailing sync separates scr reuse
  }
}

// ------------------------------------------------------- fused u1+u2 scan
// 256 WGs: bid<128 -> u1 (precomputed gx), bid>=128 -> u2 (xp on the fly,
// hidden in the r/h exchange windows; u1 runs >=2 steps ahead in steady state).
__global__ __launch_bounds__(256, 1) void uni_fused_kernel(
    const float* __restrict__ gx1,
    const unsigned short* __restrict__ w1Hi, const unsigned short* __restrict__ w1Lo,
    const unsigned short* __restrict__ w2Hi, const unsigned short* __restrict__ w2Lo,
    const float* __restrict__ bg2, const float* __restrict__ bc2,
    unsigned* __restrict__ hPk1, unsigned* __restrict__ rPk1,
    unsigned* __restrict__ hPk2, unsigned* __restrict__ rPk2,
    unsigned* __restrict__ slots1, unsigned* __restrict__ slots2,
    unsigned short* __restrict__ y1Hi, unsigned short* __restrict__ y1Lo,
    float* __restrict__ out, float* __restrict__ st1, float* __restrict__ st2) {
  __shared__ unsigned short wHi_s[3 * 8192];
  __shared__ unsigned short wLo_s[3 * 8192];
  __shared__ float scr[4][16][17];
  __shared__ float scr2[4][16][17];
  __shared__ float scr3[4][16][17];

  const int tid = threadIdx.x;
  const int lane = tid & 63;
  const int wv = tid >> 6;
  const int bid = blockIdx.x;
  const int role = (bid >= 128);
  const int g = (bid & 127) >> 5;
  const int wg = bid & 31;
  const int hs = wg << 4;
  const int b0 = g * 16;

  const unsigned short* wph = role ? w2Hi : w1Hi;
  const unsigned short* wpl = role ? w2Lo : w1Lo;
  const int ktTot = role ? 32 : 48;
  const int ktH0 = role ? 16 : 32;
  unsigned* hPk = role ? hPk2 : hPk1;
  unsigned* rPk = role ? rPk2 : rPk1;
  unsigned* myslots = (role ? slots2 : slots1) + g * 32;
  unsigned* u1gs = slots1 + g * 32;

  {
    const int nt0[3] = {wg, 32 + wg, 64 + wg};
    for (int c = 0; c < 3; ++c) {
      const unsigned short* sH = wph + ((size_t)nt0[c] * ktTot + ktH0) * 512;
      const unsigned short* sL = wpl + ((size_t)nt0[c] * ktTot + ktH0) * 512;
      unsigned short* dH = wHi_s + c * 8192;
      unsigned short* dL = wLo_s + c * 8192;
#pragma unroll
      for (int it = 0; it < 4; ++it) {
        const int o = (it * 256 + tid) * 8;
        *(s16x8*)(dH + o) = *(const s16x8*)(sH + o);
        *(s16x8*)(dL + o) = *(const s16x8*)(sL + o);
      }
    }
  }
  __syncthreads();

  const int fm = lane & 15;
  const int fkg = lane >> 4;
  const int afe = fm * 512;
  const int asw = (fm & 7) << 3;
  const int ob = tid >> 4, oj = tid & 15;
  const int ui = ob * 512 + ((hs + oj) ^ ((ob & 7) << 3));
  const size_t tileo = (size_t)g * 8192;

  auto mfma_regs = [&](int cidx, const s16x8* ah, const s16x8* al,
                       float (*dst)[16][17]) {
    f32x4 acc0 = {0.f, 0.f, 0.f, 0.f}, acc1 = {0.f, 0.f, 0.f, 0.f};
#pragma unroll
    for (int q = 0; q < 4; ++q) {
      const int kt = wv * 4 + q;
      const int wo = ((cidx * 16 + kt) * 64 + lane) * 8;
      s16x8 bh = *(const s16x8*)(wHi_s + wo);
      s16x8 bl = *(const s16x8*)(wLo_s + wo);
      if (q & 1) {
        acc1 = __builtin_amdgcn_mfma_f32_16x16x32_bf16(ah[q], bh, acc1, 0, 0, 0);
        acc1 = __builtin_amdgcn_mfma_f32_16x16x32_bf16(ah[q], bl, acc1, 0, 0, 0);
        acc1 = __builtin_amdgcn_mfma_f32_16x16x32_bf16(al[q], bh, acc1, 0, 0, 0);
      } else {
        acc0 = __builtin_amdgcn_mfma_f32_16x16x32_bf16(ah[q], bh, acc0, 0, 0, 0);
        acc0 = __builtin_amdgcn_mfma_f32_16x16x32_bf16(ah[q], bl, acc0, 0, 0, 0);
        acc0 = __builtin_amdgcn_mfma_f32_16x16x32_bf16(al[q], bh, acc0, 0, 0, 0);
      }
    }
#pragma unroll
    for (int j = 0; j < 4; ++j) dst[wv][fkg * 4 + j][fm] = acc0[j] + acc1[j];
  };

  auto mfma_xp = [&](int cidx, const s16x8* xh, const s16x8* xl,
                     float (*dst)[16][17]) {
    const int nt0[3] = {wg, 32 + wg, 64 + wg};
    f32x4 acc0 = {0.f, 0.f, 0.f, 0.f}, acc1 = {0.f, 0.f, 0.f, 0.f};
#pragma unroll
    for (int q = 0; q < 4; ++q) {
      const int kt = wv * 4 + q;
      const size_t bo = ((size_t)nt0[cidx] * 32 + kt) * 512 + lane * 8;
      s16x8 bh = *(const s16x8*)(w2Hi + bo);
      s16x8 bl = *(const s16x8*)(w2Lo + bo);
      if (q & 1) {
        acc1 = __builtin_amdgcn_mfma_f32_16x16x32_bf16(xh[q], bh, acc1, 0, 0, 0);
        acc1 = __builtin_amdgcn_mfma_f32_16x16x32_bf16(xh[q], bl, acc1, 0, 0, 0);
        acc1 = __builtin_amdgcn_mfma_f32_16x16x32_bf16(xl[q], bh, acc1, 0, 0, 0);
      } else {
        acc0 = __builtin_amdgcn_mfma_f32_16x16x32_bf16(xh[q], bh, acc0, 0, 0, 0);
        acc0 = __builtin_amdgcn_mfma_f32_16x16x32_bf16(xh[q], bl, acc0, 0, 0, 0);
        acc0 = __builtin_amdgcn_mfma_f32_16x16x32_bf16(xl[q], bh, acc0, 0, 0, 0);
      }
    }
#pragma unroll
    for (int j = 0; j < 4; ++j) dst[wv][fkg * 4 + j][fm] = acc0[j] + acc1[j];
  };

  auto load_y1_frags = [&](int t_, s16x8* xh, s16x8* xl) {
#pragma unroll
    for (int q = 0; q < 4; ++q) {
      const int kt = wv * 4 + q;
      const size_t yo = ((size_t)t_ * 64 + b0 + fm) * 512 + kt * 32 + fkg * 8;
      asm volatile("global_load_dwordx4 %0, %1, off sc0 sc1"
                   : "=v"(xh[q]) : "v"(y1Hi + yo) : "memory");
      asm volatile("global_load_dwordx4 %0, %1, off sc0 sc1"
                   : "=v"(xl[q]) : "v"(y1Lo + yo) : "memory");
    }
    vm_drain();
    __builtin_amdgcn_sched_barrier(0);
  };

  auto load_frags = [&](const unsigned* pk, s16x8* ah, s16x8* al,
                        bool withHv, unsigned* hvOut) {
    u32x4 d[4][2];
#pragma unroll
    for (int q = 0; q < 4; ++q) {
      const int kt = wv * 4 + q;
      const unsigned* p = pk + tileo + afe + ((kt * 32 + fkg * 8) ^ asw);
      asm volatile("global_load_dwordx4 %0, %1, off sc0 sc1"
                   : "=v"(d[q][0]) : "v"(p) : "memory");
      asm volatile("global_load_dwordx4 %0, %1, off sc0 sc1"
                   : "=v"(d[q][1]) : "v"(p + 4) : "memory");
    }
    if (withHv)
      asm volatile("global_load_dword %0, %1, off sc0 sc1"
                   : "=v"(*hvOut) : "v"(pk + tileo + ui) : "memory");
    vm_drain();
    __builtin_amdgcn_sched_barrier(0);
#pragma unroll
    for (int q = 0; q < 4; ++q) {
      u32x4 hh, ll;
#pragma unroll
      for (int i = 0; i < 2; ++i) {
        const u32x4 dd = d[q][i];
        hh[2 * i] = (dd[0] & 0xffffu) | (dd[1] << 16);
        hh[2 * i + 1] = (dd[2] & 0xffffu) | (dd[3] << 16);
        ll[2 * i] = (dd[0] >> 16) | (dd[1] & 0xffff0000u);
        ll[2 * i + 1] = (dd[2] >> 16) | (dd[3] & 0xffff0000u);
      }
      __builtin_memcpy(&ah[q], &hh, 16);
      __builtin_memcpy(&al[q], &ll, 16);
    }
  };

  auto poll_arr = [&](const unsigned* arr, unsigned target) {
    if (tid < 32) {
      const unsigned* p = arr + tid;
      unsigned v;
      do {
        asm volatile("global_load_dword %0, %1, off sc0 sc1\n\ts_waitcnt vmcnt(0)"
                     : "=v"(v) : "v"(p) : "memory");
      } while (!__all(v >= target));
    }
    __syncthreads();
  };

  if (role == 0) {
    // ------------------------------ U1 ------------------------------
    float gxr, gxu, gxc;
    {
      const float* row = gx1 + ((size_t)0 * 64 + b0 + ob) * 1536 + hs + oj;
      gxr = row[0]; gxu = row[512]; gxc = row[1024];
    }
    for (int t = 0; t < TT; ++t) {
      s16x8 ah[4], al[4];
      unsigned hvu = 0;
      load_frags(hPk, ah, al, true, &hvu);
      mfma_regs(0, ah, al, scr);
      __syncthreads();

      float rpre = scr[0][ob][oj] + scr[1][ob][oj] + scr[2][ob][oj] + scr[3][ob][oj] + gxr;
      float sg = sigm(rpre);
      float hv = bfu2f((unsigned short)(hvu & 0xffffu)) + bfu2f((unsigned short)(hvu >> 16));
      float rh = sg * hv;
      {
        unsigned short hh_ = f2bfu(rh);
        unsigned short ll_ = f2bfu(rh - bfu2f(hh_));
        unsigned e = (unsigned)hh_ | ((unsigned)ll_ << 16);
        asm volatile("global_store_dword %0, %1, off sc0 sc1"
                     :: "v"(rPk + tileo + ui), "v"(e) : "memory");
      }
      vm_drain();
      __syncthreads();
      if (tid == 0) {
        unsigned tv = 2 * t + 1;
        asm volatile("global_store_dword %0, %1, off sc0 sc1"
                     :: "v"(myslots + wg), "v"(tv) : "memory");
      }

      mfma_regs(1, ah, al, scr2);

      float ngxr = 0.f, ngxu = 0.f, ngxc = 0.f;
      if (t + 1 < TT) {
        const float* row = gx1 + ((size_t)(t + 1) * 64 + b0 + ob) * 1536 + hs + oj;
        ngxr = row[0]; ngxu = row[512]; ngxc = row[1024];
      }

      poll_arr(myslots, 2 * t + 1);

      load_frags(rPk, ah, al, false, nullptr);
      mfma_regs(2, ah, al, scr);
      __syncthreads();

      float upre = scr2[0][ob][oj] + scr2[1][ob][oj] + scr2[2][ob][oj] + scr2[3][ob][oj] + gxu;
      float uv = sigm(upre);
      float cpre = scr[0][ob][oj] + scr[1][ob][oj] + scr[2][ob][oj] + scr[3][ob][oj] + gxc;
      float hn = uv * hv + (1.f - uv) * tanh_fast(cpre);
      unsigned short hh_ = f2bfu(hn);
      unsigned short ll_ = f2bfu(hn - bfu2f(hh_));

      {  // y1 before drain: flag 2t+2 publishes it for u2
        const size_t yi = ((size_t)t * 64 + (b0 + ob)) * 512 + hs + oj;
        sc1_store_b16(y1Hi + yi, hh_);
        sc1_store_b16(y1Lo + yi, ll_);
      }
      if (t < TT - 1) {
        unsigned e = (unsigned)hh_ | ((unsigned)ll_ << 16);
        asm volatile("global_store_dword %0, %1, off sc0 sc1"
                     :: "v"(hPk + tileo + ui), "v"(e) : "memory");
      } else {
        st1[(size_t)(b0 + ob) * 512 + hs + oj] = hn;
      }
      vm_drain();
      __syncthreads();
      if (tid == 0) {
        unsigned tv = 2 * t + 2;
        asm volatile("global_store_dword %0, %1, off sc0 sc1"
                     :: "v"(myslots + wg), "v"(tv) : "memory");
      }
      if (t == TT - 1) break;
      gxr = ngxr; gxu = ngxu; gxc = ngxc;
      poll_arr(myslots, 2 * t + 2);
    }
  } else {
    // ------------------------------ U2 ------------------------------
    const float br = bg2[hs + oj], bu = bg2[512 + hs + oj], bc_ = bc2[hs + oj];
    s16x8 xh[4], xl[4];
    float gxr, gxu, gxc;
    {  // prologue: xp(0)
      poll_arr(u1gs, 2);
      load_y1_frags(0, xh, xl);
      mfma_xp(0, xh, xl, scr);
      mfma_xp(1, xh, xl, scr2);
      mfma_xp(2, xh, xl, scr3);
      __syncthreads();
      gxr = scr[0][ob][oj] + scr[1][ob][oj] + scr[2][ob][oj] + scr[3][ob][oj] + br;
      gxu = scr2[0][ob][oj] + scr2[1][ob][oj] + scr2[2][ob][oj] + scr2[3][ob][oj] + bu;
      gxc = scr3[0][ob][oj] + scr3[1][ob][oj] + scr3[2][ob][oj] + scr3[3][ob][oj] + bc_;
      __syncthreads();
    }
    for (int t = 0; t < TT; ++t) {
      s16x8 ah[4], al[4];
      unsigned hvu = 0;
      load_frags(hPk, ah, al, true, &hvu);
      mfma_regs(0, ah, al, scr);
      __syncthreads();

      float rpre = scr[0][ob][oj] + scr[1][ob][oj] + scr[2][ob][oj] + scr[3][ob][oj] + gxr;
      float sg = sigm(rpre);
      float hv = bfu2f((unsigned short)(hvu & 0xffffu)) + bfu2f((unsigned short)(hvu >> 16));
      float rh = sg * hv;
      {
        unsigned short hh_ = f2bfu(rh);
        unsigned short ll_ = f2bfu(rh - bfu2f(hh_));
        unsigned e = (unsigned)hh_ | ((unsigned)ll_ << 16);
        asm volatile("global_store_dword %0, %1, off sc0 sc1"
                     :: "v"(rPk + tileo + ui), "v"(e) : "memory");
      }
      vm_drain();
      __syncthreads();
      if (tid == 0) {
        unsigned tv = 2 * t + 1;
        asm volatile("global_store_dword %0, %1, off sc0 sc1"
                     :: "v"(myslots + wg), "v"(tv) : "memory");
      }

      // r-window: G1u + xp(u,c of t+1)
      mfma_regs(1, ah, al, scr2);
      float ngxr = 0.f, ngxu = 0.f, ngxc = 0.f;
      if (t + 1 < TT) {
        poll_arr(u1gs, 2 * (t + 1) + 2);    // u1 ahead: near-instant
        load_y1_frags(t + 1, xh, xl);
        mfma_xp(1, xh, xl, scr);            // u-part (scr dead after S1)
        mfma_xp(2, xh, xl, scr3);           // c-part
        __syncthreads();
        ngxu = scr[0][ob][oj] + scr[1][ob][oj] + scr[2][ob][oj] + scr[3][ob][oj] + bu;
        ngxc = scr3[0][ob][oj] + scr3[1][ob][oj] + scr3[2][ob][oj] + scr3[3][ob][oj] + bc_;
        __syncthreads();
      }

      poll_arr(myslots, 2 * t + 1);

      load_frags(rPk, ah, al, false, nullptr);
      mfma_regs(2, ah, al, scr);
      __syncthreads();

      float upre = scr2[0][ob][oj] + scr2[1][ob][oj] + scr2[2][ob][oj] + scr2[3][ob][oj] + gxu;
      float uv = sigm(upre);
      float cpre = scr[0][ob][oj] + scr[1][ob][oj] + scr[2][ob][oj] + scr[3][ob][oj] + gxc;
      float hn = uv * hv + (1.f - uv) * tanh_fast(cpre);

      if (t == TT - 1) {
        out[((size_t)(b0 + ob) * TT + t) * 512 + hs + oj] = hn;
        st2[(size_t)(b0 + ob) * 512 + hs + oj] = hn;
        break;
      }
      {
        unsigned short hh_ = f2bfu(hn);
        unsigned short ll_ = f2bfu(hn - bfu2f(hh_));
        unsigned e = (unsigned)hh_ | ((unsigned)ll_ << 16);
        asm volatile("global_store_dword %0, %1, off sc0 sc1"
                     :: "v"(hPk + tileo + ui), "v"(e) : "memory");
      }
      vm_drain();
      __syncthreads();
      if (tid == 0) {
        unsigned tv = 2 * t + 2;
        asm volatile("global_store_dword %0, %1, off sc0 sc1"
                     :: "v"(myslots + wg), "v"(tv) : "memory");
      }

      // h-window: out-write + xp(r of t+1)
      out[((size_t)(b0 + ob) * TT + t) * 512 + hs + oj] = hn;
      {
        mfma_xp(0, xh, xl, scr);            // scr dead after S2
        __syncthreads();
        ngxr = scr[0][ob][oj] + scr[1][ob][oj] + scr[2][ob][oj] + scr[3][ob][oj] + br;
      }
      gxr = ngxr; gxu = ngxu; gxc = ngxc;
      poll_arr(myslots, 2 * t + 2);         // trailing sync separates scr reuse
    }
  }
}

// ---------------------------------------------------------------- launcher
extern "C" void kernel_launch(void* const* d_in, const int* in_sizes, int n_in,
                              void* d_out, int out_size, void* d_ws, size_t ws_size,
                              hipStream_t stream) {
  (void)in_sizes; (void)n_in; (void)out_size; (void)ws_size;
  const int* x = (const int*)d_in[0];
  const float* emb = (const float*)d_in[1];
  const float* WgFw = (const float*)d_in[2];
  const float* bgFw = (const float*)d_in[3];
  const float* WcFw = (const float*)d_in[4];
  const float* bcFw = (const float*)d_in[5];
  const float* WgBw = (const float*)d_in[6];
  const float* bgBw = (const float*)d_in[7];
  const float* WcBw = (const float*)d_in[8];
  const float* bcBw = (const float*)d_in[9];
  const float* WgU1 = (const float*)d_in[10];
  const float* bgU1 = (const float*)d_in[11];
  const float* WcU1 = (const float*)d_in[12];
  const float* bcU1 = (const float*)d_in[13];
  const float* WgU2 = (const float*)d_in[14];
  const float* bgU2 = (const float*)d_in[15];
  const float* WcU2 = (const float*)d_in[16];
  const float* bcU2 = (const float*)d_in[17];

  char* ws = (char*)d_ws;
  float* bufA = (float*)(ws + 0);                    // u1 preacts 39,321,600
  unsigned short* ycatHi = (unsigned short*)(ws + 78643200);   // 13,107,200
  unsigned short* ycatLo = (unsigned short*)(ws + 91750400);   // 13,107,200
  unsigned short* y1Hi = (unsigned short*)(ws + 78643200);     // overlay (ycat dead)
  unsigned short* y1Lo = (unsigned short*)(ws + 85196800);
  unsigned short* wpFwHi = (unsigned short*)(ws + 104857600);  // 3,145,728 each
  unsigned short* wpFwLo = (unsigned short*)(ws + 108003328);
  unsigned short* wpBwHi = (unsigned short*)(ws + 111149056);
  unsigned short* wpBwLo = (unsigned short*)(ws + 114294784);
  unsigned short* wpU1Hi = (unsigned short*)(ws + 117440512);  // 4,718,592 each
  unsigned short* wpU1Lo = (unsigned short*)(ws + 122159104);
  unsigned short* wpU2Hi = (unsigned short*)(ws + 104857600);  // overlay wpFw after bidir
  unsigned short* wpU2Lo = (unsigned short*)(ws + 108003328);
  unsigned* tiles = (unsigned*)(ws + 126877696);     // 524,288 B
  unsigned* bars = (unsigned*)(ws + 127401984);      // 4,096 B

  unsigned* hPkB = tiles;               // bidir: 8 groups
  unsigned* rPkB = tiles + 65536;
  unsigned* hPk1 = tiles;               // fused: 4 groups each
  unsigned* rPk1 = tiles + 32768;
  unsigned* hPk2 = tiles + 65536;
  unsigned* rPk2 = tiles + 98304;

  float* out = (float*)d_out;
  float* st1 = out + (size_t)64 * TT * 512;
  float* st2 = st1 + 64 * 512;

  hipMemsetAsync(bars, 0, 4096, stream);

  pack_w_kernel<<<768, 256, 0, stream>>>(WgFw, WcFw, 1024, 512, 32, wpFwHi, wpFwLo);
  pack_w_kernel<<<768, 256, 0, stream>>>(WgBw, WcBw, 1024, 512, 32, wpBwHi, wpBwLo);
  pack_w_kernel<<<1152, 256, 0, stream>>>(WgU1, WcU1, 1024, 512, 48, wpU1Hi, wpU1Lo);

  hipMemsetAsync(tiles, 0, 524288, stream);
  {  // bidirectional scan (fused embedding + x-projection) -> ycat planes
    const int* xt = x;
    const float* em = emb;
    const unsigned short *w0 = wpFwHi, *w1 = wpFwLo, *w2 = wpBwHi, *w3 = wpBwLo;
    const float *bF = bgFw, *cF = bcFw, *bB = bgBw, *cB = bcBw;
    unsigned *h0 = hPkB, *r0 = rPkB;
    unsigned* bp = bars;
    unsigned short *yh = ycatHi, *yl = ycatLo;
    void* args[] = {&xt, &em, &w0, &w1, &w2, &w3, &bF, &cF, &bB, &cB,
                    &h0, &r0, &bp, &yh, &yl};
    hipLaunchCooperativeKernel((const void*)bidir_scan_kernel, dim3(256), dim3(256),
                               args, 0, stream);
  }

  // u2 pack overlays wpFw (bidir done with those weights)
  pack_w_kernel<<<768, 256, 0, stream>>>(WgU2, WcU2, 1024, 512, 32, wpU2Hi, wpU2Lo);

  // u1 input projections: A = ycat planes [6400][1024]
  gemm_mfma<1><<<dim3(50, 12), 256, 0, stream>>>(
      nullptr, nullptr, ycatHi, ycatLo, 1024, wpU1Hi, wpU1Lo, 48, 32, bgU1, bcU1, bufA);

  hipMemsetAsync(tiles, 0, 524288, stream);
  {  // fused u1 + u2 scan
    const float* a0 = bufA;
    const unsigned short *w0 = wpU1Hi, *w1 = wpU1Lo, *w2 = wpU2Hi, *w3 = wpU2Lo;
    const float *b2 = bgU2, *c2 = bcU2;
    unsigned *h1 = hPk1, *r1 = rPk1, *h2 = hPk2, *r2 = rPk2;
    unsigned *s1p = bars + 256, *s2p = bars + 384;
    unsigned short *yh = y1Hi, *yl = y1Lo;
    float *op = out, *t1 = st1, *t2 = st2;
    void* args[] = {&a0, &w0, &w1, &w2, &w3, &b2, &c2,
                    &h1, &r1, &h2, &r2, &s1p, &s2p, &yh, &yl, &op, &t1, &t2};
    hipLaunchCooperativeKernel((const void*)uni_fused_kernel, dim3(256), dim3(256),
                               args, 0, stream);
  }
}